// Round 2
// baseline (2255.789 us; speedup 1.0000x reference)
//
#include <hip/hip_runtime.h>
#include <hip/hip_bf16.h>

#define N_NODES 100000
#define N_EDGES 1600000
#define F_IN 128
#define HID 64
#define N_GRAPHS 1024

// fine dst-partition: bucket = dst>>9 (512 nodes/bucket)
#define SH 9
#define NBU 196        // buckets used: ceil(100000/512)
#define NB 200         // allocated
#define BCAP 9728      // mean 8192 + 17 sigma
#define EPB 8192       // edges per k_part block (196 blocks exactly)
#define NSLICE 4       // 4 feature slices x 16 feats; slice table = 3.2 MB (fits XCD L2)

typedef __attribute__((ext_vector_type(8))) short bf16x8;
typedef __attribute__((ext_vector_type(4))) float f32x4;
typedef __attribute__((ext_vector_type(4))) unsigned int u32x4;

// ---------------- bf16 bit helpers --------------------------------------------
__device__ __forceinline__ unsigned short f2bf(float f) {
    __hip_bfloat16 h = __float2bfloat16(f);   // RNE
    return *reinterpret_cast<unsigned short*>(&h);
}
__device__ __forceinline__ float bf2f(unsigned int u) {
    return __uint_as_float(u << 16);
}

// ---------------- dual-path load helpers (wire dtype resolved at runtime) -----
__device__ __forceinline__ float loadf(const void* p, size_t i, int f32) {
    if (f32) return ((const float*)p)[i];
    return __bfloat162float(((const __hip_bfloat16*)p)[i]);
}
__device__ __forceinline__ int loadi(const void* p, size_t i, int i64) {
    if (i64) return (int)((const long long*)p)[i];
    return ((const int*)p)[i];
}

// ---------------- init: wire detect + zero small counters ---------------------
__global__ void k_init(const unsigned int* __restrict__ xw_,
                       const unsigned int* __restrict__ ei_,
                       int* __restrict__ flags,
                       int* __restrict__ gcnt, int* __restrict__ bcnt) {
    __shared__ int cnt_f, cnt_i;
    int t = threadIdx.x;
    if (t == 0) { cnt_f = 0; cnt_i = 0; }
    __syncthreads();
    unsigned int w = xw_[t];
    unsigned int e = (w >> 7) & 0xFFu;
    if (e >= 100u && e <= 140u) atomicAdd(&cnt_f, 1);
    unsigned int iw = ei_[2 * t + 1];
    if (iw == 0u) atomicAdd(&cnt_i, 1);
    for (int i = t; i < N_GRAPHS; i += 256) gcnt[i] = 0;
    for (int i = t; i < NB; i += 256) bcnt[i] = 0;
    __syncthreads();
    if (t == 0) {
        flags[0] = (cnt_f < 180) ? 1 : 0;   // 1 => fp32 wire
        flags[1] = (cnt_i >= 128) ? 1 : 0;  // 1 => int64 wire
    }
}

// ---------------- phase A: partition by dst>>9, two-pass fat blocks -----------
__global__ __launch_bounds__(256) void k_part(const void* __restrict__ ei,
                                              const void* __restrict__ batch,
                                              int* __restrict__ bcnt,
                                              int* __restrict__ gcnt,
                                              unsigned int* __restrict__ packed,
                                              const int* __restrict__ flags) {
    int I64 = flags[1];
    __shared__ int hist[NB];
    __shared__ int base[NB];
    __shared__ int ghist[N_GRAPHS];   // 4 KB
    int t = threadIdx.x;
    if (t < NB) hist[t] = 0;
    for (int i = t; i < N_GRAPHS; i += 256) ghist[i] = 0;
    __syncthreads();
    // batch counting: block covers nodes [blk*512, blk*512+512)
    for (int it = 0; it < 2; ++it) {
        int n = blockIdx.x * 512 + it * 256 + t;
        if (n < N_NODES) atomicAdd(&ghist[loadi(batch, n, I64)], 1);
    }
    // edge pass 1: bucket counts
    int e0 = blockIdx.x * EPB;
#pragma unroll 4
    for (int it = 0; it < EPB / 256; ++it) {
        int e = e0 + it * 256 + t;
        if (e < N_EDGES) {
            int d = loadi(ei, (size_t)N_EDGES + e, I64);
            atomicAdd(&hist[d >> SH], 1);
        }
    }
    __syncthreads();
    if (t < NB) {
        base[t] = hist[t] ? atomicAdd(&bcnt[t], hist[t]) : 0;
        hist[t] = 0;   // reuse as pass-2 rank counter
    }
    for (int i = t; i < N_GRAPHS; i += 256)
        if (ghist[i]) atomicAdd(&gcnt[i], ghist[i]);
    __syncthreads();
    // edge pass 2: rank + write
#pragma unroll 4
    for (int it = 0; it < EPB / 256; ++it) {
        int e = e0 + it * 256 + t;
        if (e < N_EDGES) {
            int s = loadi(ei, e, I64);
            int d = loadi(ei, (size_t)N_EDGES + e, I64);
            int b = d >> SH;
            int r = atomicAdd(&hist[b], 1);
            int pos = base[b] + r;
            if (pos < BCAP)
                packed[(size_t)b * BCAP + pos] = ((unsigned int)s << SH) | (unsigned int)(d & 511);
        }
    }
}

// ---------------- hist: in-degree -> dis only ---------------------------------
__global__ __launch_bounds__(256) void k_hist(const unsigned int* __restrict__ packed,
                                              const int* __restrict__ bcnt,
                                              float* __restrict__ dis) {
    __shared__ int hist[512];
    int b = blockIdx.x;
    int t = threadIdx.x;
    int n = bcnt[b];
    if (n > BCAP) n = BCAP;
    for (int i = t; i < 512; i += 256) hist[i] = 0;
    __syncthreads();
    const unsigned int* pb = packed + (size_t)b * BCAP;
    for (int i = t; i < n; i += 256)
        atomicAdd(&hist[pb[i] & 511u], 1);
    __syncthreads();
    int nbase = b << SH;
    for (int i = t; i < 512; i += 256) {
        int node = nbase + i;
        if (node < N_NODES)
            dis[node] = rsqrtf((float)hist[i] + 1.0f);
    }
}

// ---------------- graph scan: gcnt (1024) -> gptr, one block ------------------
__global__ void k_gscan(const int* __restrict__ gcnt, int* __restrict__ gptr) {
    __shared__ int s[512];
    int t = threadIdx.x;
    int a = gcnt[2 * t], bq = gcnt[2 * t + 1];
    int ps = a + bq;
    s[t] = ps;
    __syncthreads();
    for (int off = 1; off < 512; off <<= 1) {
        int x = (t >= off) ? s[t - off] : 0;
        __syncthreads();
        s[t] += x;
        __syncthreads();
    }
    int excl = s[t] - ps;
    gptr[2 * t] = excl;
    gptr[2 * t + 1] = excl + a;
    if (t == 511) gptr[1024] = s[511];
}

// ---------------- MFMA GEMM: in[N,K] @ W[K,64] -> out slice-major bf16 --------
// out layout: [4 slices][N_NODES][16 feats] bf16: slice s is a contiguous
// 3.2 MB block -> fits a single XCD L2 during aggregation.
template <int K>
__global__ __launch_bounds__(256) void k_gemm(const void* __restrict__ x,
                                              const void* __restrict__ W,
                                              const float* __restrict__ dis,
                                              unsigned short* __restrict__ out,  // bf16 bits
                                              const int* __restrict__ flags,
                                              int x_is_f32, int in_sm) {
    int Wf32 = flags[0];
    int xF32 = (x_is_f32 < 0) ? Wf32 : x_is_f32;
    __shared__ unsigned short Wt[64][K + 8];
    __shared__ unsigned short xs[32][K + 8];
    int t = threadIdx.x;
    int wave = t >> 6, lane = t & 63;
    int quad = lane >> 4, l16 = lane & 15;

    for (int id = t; id < 64 * K; id += 256) {
        int k = id >> 6, n = id & 63;
        Wt[n][k] = f2bf(loadf(W, id, Wf32));
    }
    __syncthreads();

    bf16x8 bfrag[K / 32];
#pragma unroll
    for (int c = 0; c < K / 32; ++c)
        bfrag[c] = *reinterpret_cast<bf16x8*>(&Wt[wave * 16 + l16][c * 32 + quad * 8]);

    const int ngroups = (N_NODES + 31) / 32;
    for (int g = blockIdx.x; g < ngroups; g += gridDim.x) {
        __syncthreads();
        int row0 = g * 32;
        if (in_sm) {
            // slice-major input (K==64): 64 consecutive threads read 1 KB
            // contiguous per slice (rows are 32 B apart within a slice).
            for (int cid = t; cid < 4 * K; cid += 256) {
                int slice = cid >> 6, i = cid & 63;
                int rr = i >> 1, half = i & 1;
                int r = row0 + rr;
                u32x4 val = {0u, 0u, 0u, 0u};
                if (r < N_NODES)
                    val = ((const u32x4*)x)[((size_t)slice * N_NODES + row0) * 2 + i];
                *reinterpret_cast<u32x4*>(&xs[rr][slice * 16 + half * 8]) = val;
            }
        } else {
            for (int cid = t; cid < 4 * K; cid += 256) {
                int rr = cid / (K / 8), c8 = cid % (K / 8);
                int r = row0 + rr;
                u32x4 val = {0u, 0u, 0u, 0u};
                if (r < N_NODES) {
                    size_t base = (size_t)r * K + c8 * 8;
                    if (xF32) {
                        const u32x4* xp = (const u32x4*)x;
                        u32x4 q0 = xp[base / 4];
                        u32x4 q1 = xp[base / 4 + 1];
                        val.x = f2bf(__uint_as_float(q0.x)) | ((unsigned int)f2bf(__uint_as_float(q0.y)) << 16);
                        val.y = f2bf(__uint_as_float(q0.z)) | ((unsigned int)f2bf(__uint_as_float(q0.w)) << 16);
                        val.z = f2bf(__uint_as_float(q1.x)) | ((unsigned int)f2bf(__uint_as_float(q1.y)) << 16);
                        val.w = f2bf(__uint_as_float(q1.z)) | ((unsigned int)f2bf(__uint_as_float(q1.w)) << 16);
                    } else {
                        val = ((const u32x4*)x)[base / 8];
                    }
                }
                *reinterpret_cast<u32x4*>(&xs[rr][c8 * 8]) = val;
            }
        }
        __syncthreads();

        f32x4 acc0 = {0.f, 0.f, 0.f, 0.f};
        f32x4 acc1 = {0.f, 0.f, 0.f, 0.f};
#pragma unroll
        for (int c = 0; c < K / 32; ++c) {
            bf16x8 a0 = *reinterpret_cast<bf16x8*>(&xs[l16][c * 32 + quad * 8]);
            bf16x8 a1 = *reinterpret_cast<bf16x8*>(&xs[16 + l16][c * 32 + quad * 8]);
            acc0 = __builtin_amdgcn_mfma_f32_16x16x32_bf16(a0, bfrag[c], acc0, 0, 0, 0);
            acc1 = __builtin_amdgcn_mfma_f32_16x16x32_bf16(a1, bfrag[c], acc1, 0, 0, 0);
        }
        // col = wave*16 + l16 -> slice = wave, within-slice feat = l16
        unsigned short* ow = out + (size_t)wave * (N_NODES * 16);
#pragma unroll
        for (int reg = 0; reg < 4; ++reg) {
            int r0 = row0 + quad * 4 + reg;
            if (r0 < N_NODES) ow[(size_t)r0 * 16 + l16] = f2bf(acc0[reg] * dis[r0]);
            int r1 = row0 + 16 + quad * 4 + reg;
            if (r1 < N_NODES) ow[(size_t)r1 * 16 + l16] = f2bf(acc1[reg] * dis[r1]);
        }
    }
}

// ---------------- edge-parallel bucketed aggregation --------------------------
// grid = 98*8 = 784 blocks. XCD-affine: xcd = blk&7, slice = xcd>>1 -> each XCD
// touches ONE 3.2 MB slice (L2-resident). bucket = (blk>>3)*2+(xcd&1).
// R1 fix: unsafeAtomicAdd on __shared__ lowered to the flat/CAS path (680 us,
// VALUBusy 2.6%) -> plain atomicAdd on the __shared__ array = native ds_add_f32.
// Gather pipeline deepened 4 -> 8 in-flight 32-B row reads per wave.
__global__ __launch_bounds__(256) void k_agg(const unsigned int* __restrict__ packed,
                                             const int* __restrict__ bcnt,
                                             const float* __restrict__ dis,
                                             const unsigned short* __restrict__ xws,
                                             const void* __restrict__ bias,
                                             unsigned short* __restrict__ out,
                                             int do_relu,
                                             const int* __restrict__ flags) {
    int F32 = flags[0];
    __shared__ float acc[512 * 17];
    int blk = blockIdx.x;
    int xcd = blk & 7;
    int s = xcd >> 1;                              // slice 0..3
    int bkt = ((blk >> 3) << 1) | (xcd & 1);       // 0..195
    int t = threadIdx.x;
    for (int i = t; i < 512 * 17; i += 256) acc[i] = 0.f;
    __syncthreads();

    int n = bcnt[bkt];
    if (n > BCAP) n = BCAP;
    const unsigned int* pb = packed + (size_t)bkt * BCAP;
    const unsigned int* xs = (const unsigned int*)(xws + (size_t)s * N_NODES * 16); // u32 = 2 feats
    int lane = t & 63, wave = t >> 6;
    int eg = lane >> 3;       // edge-in-group 0..7
    int k = lane & 7;         // feature-pair 0..7

    for (int i0 = wave * 64; i0 < n; i0 += 256) {  // 4 waves x 8 x 8 edges
        unsigned int p[8], v[8];
        int ok[8];
#pragma unroll
        for (int u = 0; u < 8; ++u) {
            int e = i0 + u * 8 + eg;
            ok[u] = (e < n);
            p[u] = ok[u] ? pb[e] : 0u;
        }
#pragma unroll
        for (int u = 0; u < 8; ++u)
            v[u] = ok[u] ? xs[(size_t)(p[u] >> SH) * 8 + k] : 0u;
#pragma unroll
        for (int u = 0; u < 8; ++u) {
            if (ok[u]) {
                int d9 = (int)(p[u] & 511u);
                atomicAdd(&acc[d9 * 17 + 2 * k],     bf2f(v[u] & 0xFFFFu));
                atomicAdd(&acc[d9 * 17 + 2 * k + 1], bf2f(v[u] >> 16));
            }
        }
    }
    __syncthreads();

    int nbase = bkt << SH;
    for (int idx = t; idx < 512 * 8; idx += 256) {
        int n9 = idx >> 3, kk = idx & 7;
        int node = nbase + n9;
        if (node >= N_NODES) continue;
        unsigned int sv = xs[(size_t)node * 8 + kk];      // self row (L2-hot)
        float d = dis[node];
        float b0 = loadf(bias, s * 16 + 2 * kk, F32);
        float b1 = loadf(bias, s * 16 + 2 * kk + 1, F32);
        float v0 = fmaf(acc[n9 * 17 + 2 * kk]     + bf2f(sv & 0xFFFFu), d, b0);
        float v1 = fmaf(acc[n9 * 17 + 2 * kk + 1] + bf2f(sv >> 16),     d, b1);
        if (do_relu) { v0 = fmaxf(v0, 0.f); v1 = fmaxf(v1, 0.f); }
        ((unsigned int*)out)[(size_t)s * N_NODES * 8 + (size_t)node * 8 + kk] =
            (unsigned int)f2bf(v0) | ((unsigned int)f2bf(v1) << 16);
    }
}

// ---------------- fused mean-pool + linear head (4 graphs/block) --------------
__global__ __launch_bounds__(256) void k_pool_final(const int* __restrict__ gptr,
                             const unsigned short* __restrict__ h,   // slice-major
                             const void* __restrict__ Wl, const void* __restrict__ bl,
                             void* __restrict__ out, const int* __restrict__ flags) {
    int F32 = flags[0];
    int g = blockIdx.x * 4 + (threadIdx.x >> 6);
    int lane = threadIdx.x & 63;
    if (g >= N_GRAPHS) return;
    int s = gptr[g], e = gptr[g + 1];
    size_t hbase = (size_t)(lane >> 4) * N_NODES * 16 + (lane & 15);
    float acc = 0.0f;
    for (int n = s; n < e; ++n) acc += bf2f(h[hbase + (size_t)n * 16]);
    float cnt = fmaxf((float)(e - s), 1.0f);
    float v = (acc / cnt) * loadf(Wl, lane, F32);
#pragma unroll
    for (int o = 32; o > 0; o >>= 1) v += __shfl_down(v, o, 64);
    if (lane == 0) {
        float r = v + loadf(bl, 0, F32);
        if (F32) ((float*)out)[g] = r;
        else     ((__hip_bfloat16*)out)[g] = __float2bfloat16(r);
    }
}

extern "C" void kernel_launch(void* const* d_in, const int* in_sizes, int n_in,
                              void* d_out, int out_size, void* d_ws, size_t ws_size,
                              hipStream_t stream) {
    const void* x     = d_in[0];
    const void* ei    = d_in[1];
    const void* batch = d_in[2];
    const void* W1 = d_in[3];
    const void* b1 = d_in[4];
    const void* W2 = d_in[5];
    const void* b2 = d_in[6];
    const void* W3 = d_in[7];
    const void* b3 = d_in[8];
    const void* Wl = d_in[9];
    const void* bl = d_in[10];

    // workspace layout (~34 MB)
    float* dis   = (float*)d_ws;             // 100352
    int*   gcnt  = (int*)(dis + 100352);     // 1024
    int*   gptr  = gcnt + 1024;              // 1056 (needs 1025)
    int*   bcnt  = gptr + 1056;              // 256
    int*   flags = bcnt + 256;               // 16
    unsigned int* packed = (unsigned int*)(flags + 16);    // NB*BCAP (7.8 MB)
    unsigned short* bufA = (unsigned short*)(packed + (size_t)NB * BCAP);  // bf16 slice-major (12.8 MB)
    unsigned short* bufB = bufA + (size_t)NSLICE * N_NODES * 16;           // bf16 slice-major (12.8 MB)

    const int TB = 256;
    dim3 blk(TB);

    // init: detect + zero small counters
    k_init<<<1, blk, 0, stream>>>((const unsigned int*)x, (const unsigned int*)ei,
                                  flags, gcnt, bcnt);
    // phase A partition (two-pass fat blocks, + batch counts)
    k_part<<<(N_EDGES + EPB - 1) / EPB, blk, 0, stream>>>(ei, batch, bcnt, gcnt, packed, flags);
    // in-degree -> dis
    k_hist<<<NBU, blk, 0, stream>>>(packed, bcnt, dis);
    // graph scan -> gptr
    k_gscan<<<1, 512, 0, stream>>>(gcnt, gptr);

    // ---- layer 1 ----
    k_gemm<F_IN><<<1024, blk, 0, stream>>>(x, W1, dis, bufA, flags, -1, 0);
    k_agg<<<98 * 8, blk, 0, stream>>>(packed, bcnt, dis, bufA, b1, bufB, 1, flags);
    // ---- layer 2 ----
    k_gemm<HID><<<1024, blk, 0, stream>>>(bufB, W2, dis, bufA, flags, 0, 1);
    k_agg<<<98 * 8, blk, 0, stream>>>(packed, bcnt, dis, bufA, b2, bufB, 1, flags);
    // ---- layer 3 ----
    k_gemm<HID><<<1024, blk, 0, stream>>>(bufB, W3, dis, bufA, flags, 0, 1);
    k_agg<<<98 * 8, blk, 0, stream>>>(packed, bcnt, dis, bufA, b3, bufB, 0, flags);

    // ---- pool + head ----
    k_pool_final<<<N_GRAPHS / 4, blk, 0, stream>>>(gptr, bufB, Wl, bl, d_out, flags);
}

// Round 3
// 566.176 us; speedup vs baseline: 3.9843x; 3.9843x over previous
//
#include <hip/hip_runtime.h>
#include <hip/hip_bf16.h>

#define N_NODES 100000
#define N_EDGES 1600000
#define F_IN 128
#define HID 64
#define N_GRAPHS 1024

// fine dst-partition: bucket = dst>>9 (512 nodes/bucket)
#define SH 9
#define NBU 196        // buckets used: ceil(100000/512)
#define NB 200         // allocated
#define BCAP 9728      // mean 8192 + 17 sigma
#define EPB 8192       // edges per k_part block (196 blocks exactly)
#define NSLICE 4       // 4 feature slices x 16 feats; slice table = 3.2 MB (fits XCD L2)

typedef __attribute__((ext_vector_type(8))) short bf16x8;
typedef __attribute__((ext_vector_type(4))) float f32x4;
typedef __attribute__((ext_vector_type(4))) unsigned int u32x4;

// ---------------- bf16 bit helpers --------------------------------------------
__device__ __forceinline__ unsigned short f2bf(float f) {
    __hip_bfloat16 h = __float2bfloat16(f);   // RNE
    return *reinterpret_cast<unsigned short*>(&h);
}
__device__ __forceinline__ float bf2f(unsigned int u) {
    return __uint_as_float(u << 16);
}

// ---------------- dual-path load helpers (wire dtype resolved at runtime) -----
__device__ __forceinline__ float loadf(const void* p, size_t i, int f32) {
    if (f32) return ((const float*)p)[i];
    return __bfloat162float(((const __hip_bfloat16*)p)[i]);
}
__device__ __forceinline__ int loadi(const void* p, size_t i, int i64) {
    if (i64) return (int)((const long long*)p)[i];
    return ((const int*)p)[i];
}

// ---------------- init: wire detect + zero small counters ---------------------
__global__ void k_init(const unsigned int* __restrict__ xw_,
                       const unsigned int* __restrict__ ei_,
                       int* __restrict__ flags,
                       int* __restrict__ gcnt, int* __restrict__ bcnt) {
    __shared__ int cnt_f, cnt_i;
    int t = threadIdx.x;
    if (t == 0) { cnt_f = 0; cnt_i = 0; }
    __syncthreads();
    unsigned int w = xw_[t];
    unsigned int e = (w >> 7) & 0xFFu;
    if (e >= 100u && e <= 140u) atomicAdd(&cnt_f, 1);
    unsigned int iw = ei_[2 * t + 1];
    if (iw == 0u) atomicAdd(&cnt_i, 1);
    for (int i = t; i < N_GRAPHS; i += 256) gcnt[i] = 0;
    for (int i = t; i < NB; i += 256) bcnt[i] = 0;
    __syncthreads();
    if (t == 0) {
        flags[0] = (cnt_f < 180) ? 1 : 0;   // 1 => fp32 wire
        flags[1] = (cnt_i >= 128) ? 1 : 0;  // 1 => int64 wire
    }
}

// ---------------- phase A: partition by dst>>9, two-pass fat blocks -----------
__global__ __launch_bounds__(256) void k_part(const void* __restrict__ ei,
                                              const void* __restrict__ batch,
                                              int* __restrict__ bcnt,
                                              int* __restrict__ gcnt,
                                              unsigned int* __restrict__ packed,
                                              const int* __restrict__ flags) {
    int I64 = flags[1];
    __shared__ int hist[NB];
    __shared__ int base[NB];
    __shared__ int ghist[N_GRAPHS];   // 4 KB
    int t = threadIdx.x;
    if (t < NB) hist[t] = 0;
    for (int i = t; i < N_GRAPHS; i += 256) ghist[i] = 0;
    __syncthreads();
    // batch counting: block covers nodes [blk*512, blk*512+512)
    for (int it = 0; it < 2; ++it) {
        int n = blockIdx.x * 512 + it * 256 + t;
        if (n < N_NODES) atomicAdd(&ghist[loadi(batch, n, I64)], 1);
    }
    // edge pass 1: bucket counts
    int e0 = blockIdx.x * EPB;
#pragma unroll 4
    for (int it = 0; it < EPB / 256; ++it) {
        int e = e0 + it * 256 + t;
        if (e < N_EDGES) {
            int d = loadi(ei, (size_t)N_EDGES + e, I64);
            atomicAdd(&hist[d >> SH], 1);
        }
    }
    __syncthreads();
    if (t < NB) {
        base[t] = hist[t] ? atomicAdd(&bcnt[t], hist[t]) : 0;
        hist[t] = 0;   // reuse as pass-2 rank counter
    }
    for (int i = t; i < N_GRAPHS; i += 256)
        if (ghist[i]) atomicAdd(&gcnt[i], ghist[i]);
    __syncthreads();
    // edge pass 2: rank + write
#pragma unroll 4
    for (int it = 0; it < EPB / 256; ++it) {
        int e = e0 + it * 256 + t;
        if (e < N_EDGES) {
            int s = loadi(ei, e, I64);
            int d = loadi(ei, (size_t)N_EDGES + e, I64);
            int b = d >> SH;
            int r = atomicAdd(&hist[b], 1);
            int pos = base[b] + r;
            if (pos < BCAP)
                packed[(size_t)b * BCAP + pos] = ((unsigned int)s << SH) | (unsigned int)(d & 511);
        }
    }
}

// ---------------- hist: in-degree + dis + scan partials (fused) ---------------
__global__ __launch_bounds__(256) void k_hist(const unsigned int* __restrict__ packed,
                                              const int* __restrict__ bcnt,
                                              int* __restrict__ cnt,
                                              float* __restrict__ dis,
                                              int* __restrict__ partN) {
    __shared__ int hist[512];
    int b = blockIdx.x;
    int t = threadIdx.x;
    int n = bcnt[b];
    if (n > BCAP) n = BCAP;
    for (int i = t; i < 512; i += 256) hist[i] = 0;
    __syncthreads();
    const unsigned int* pb = packed + (size_t)b * BCAP;
    for (int i = t; i < n; i += 256)
        atomicAdd(&hist[pb[i] & 511u], 1);
    __syncthreads();
    int nbase = b << SH;
    for (int i = t; i < 512; i += 256) {
        int node = nbase + i;
        if (node < N_NODES) {
            int c = hist[i];
            cnt[node] = c;
            dis[node] = rsqrtf((float)c + 1.0f);
        }
    }
    __syncthreads();
    for (int off = 128; off > 0; off >>= 1) {
        if (t < off) { hist[t] += hist[t + off]; hist[256 + t] += hist[256 + t + off]; }
        __syncthreads();
    }
    if (t == 0) {
        partN[2 * b] = hist[0];
        if (2 * b + 1 < 391) partN[2 * b + 1] = hist[256];
    }
}

// ---------------- middle scan: partN (391) + graph scan (1024), one block -----
__global__ void k_scan_mid(int* __restrict__ partial, int nb,
                           int* __restrict__ rp, int n,
                           const int* __restrict__ gcnt, int* __restrict__ gptr) {
    __shared__ int s[512];
    int t = threadIdx.x;
    int v = (t < nb) ? partial[t] : 0;
    s[t] = v;
    __syncthreads();
    for (int off = 1; off < 512; off <<= 1) {
        int x = (t >= off) ? s[t - off] : 0;
        __syncthreads();
        s[t] += x;
        __syncthreads();
    }
    if (t < nb) partial[t] = s[t] - v;   // exclusive
    if (t == 511) rp[n] = s[511];        // grand total
    __syncthreads();
    int a = gcnt[2 * t], bq = gcnt[2 * t + 1];
    int ps = a + bq;
    s[t] = ps;
    __syncthreads();
    for (int off = 1; off < 512; off <<= 1) {
        int x = (t >= off) ? s[t - off] : 0;
        __syncthreads();
        s[t] += x;
        __syncthreads();
    }
    int excl = s[t] - ps;
    gptr[2 * t] = excl;
    gptr[2 * t + 1] = excl + a;
    if (t == 511) gptr[1024] = s[511];
}

// ---------------- scan p3: per-256-chunk local scan + offset -> rp ------------
__global__ void k_scan_p3(const int* __restrict__ in, const int* __restrict__ partial,
                          int* __restrict__ out, int n) {
    __shared__ int s[256];
    int t = threadIdx.x;
    int i = blockIdx.x * 256 + t;
    int v = (i < n) ? in[i] : 0;
    s[t] = v;
    __syncthreads();
    for (int off = 1; off < 256; off <<= 1) {
        int x = (t >= off) ? s[t - off] : 0;
        __syncthreads();
        s[t] += x;
        __syncthreads();
    }
    if (i < n) out[i] = partial[blockIdx.x] + s[t] - v;
}

// ---------------- phase B: LDS counting-sort, dense csr writes ----------------
__global__ __launch_bounds__(512) void k_bucketcsr(const unsigned int* __restrict__ packed,
                                                   const int* __restrict__ bcnt,
                                                   const int* __restrict__ rp,
                                                   int* __restrict__ csr) {
    __shared__ int offs[512];
    __shared__ int elds[BCAP];    // 38 KB
    int b = blockIdx.x;
    int nbase = b << SH;
    int base = rp[nbase];
    int lim = nbase + 512; if (lim > N_NODES) lim = N_NODES;
    int nedge = rp[lim] - base;
    if (nedge > BCAP) nedge = BCAP;
    for (int i = threadIdx.x; i < 512; i += 512) {
        int node = nbase + i;
        offs[i] = (node < N_NODES) ? (rp[node] - base) : nedge;
    }
    __syncthreads();
    int n = bcnt[b]; if (n > BCAP) n = BCAP;
    const unsigned int* pb = packed + (size_t)b * BCAP;
    for (int i = threadIdx.x; i < n; i += 512) {
        unsigned int p = pb[i];
        int pos = atomicAdd(&offs[p & 511u], 1);
        if (pos < BCAP) elds[pos] = (int)(p >> SH);
    }
    __syncthreads();
    for (int i = threadIdx.x; i < nedge; i += 512)
        csr[base + i] = elds[i];
}

// ---------------- MFMA GEMM: in[N,K] @ W[K,64] -> out slice-major bf16 --------
// out layout: [4 slices][N_NODES][16 feats] bf16: slice s is a contiguous
// 3.2 MB block -> fits a single XCD L2 during aggregation.
template <int K>
__global__ __launch_bounds__(256) void k_gemm(const void* __restrict__ x,
                                              const void* __restrict__ W,
                                              const float* __restrict__ dis,
                                              unsigned short* __restrict__ out,  // bf16 bits
                                              const int* __restrict__ flags,
                                              int x_is_f32, int in_sm) {
    int Wf32 = flags[0];
    int xF32 = (x_is_f32 < 0) ? Wf32 : x_is_f32;
    __shared__ unsigned short Wt[64][K + 8];
    __shared__ unsigned short xs[32][K + 8];
    int t = threadIdx.x;
    int wave = t >> 6, lane = t & 63;
    int quad = lane >> 4, l16 = lane & 15;

    for (int id = t; id < 64 * K; id += 256) {
        int k = id >> 6, n = id & 63;
        Wt[n][k] = f2bf(loadf(W, id, Wf32));
    }
    __syncthreads();

    bf16x8 bfrag[K / 32];
#pragma unroll
    for (int c = 0; c < K / 32; ++c)
        bfrag[c] = *reinterpret_cast<bf16x8*>(&Wt[wave * 16 + l16][c * 32 + quad * 8]);

    const int ngroups = (N_NODES + 31) / 32;
    for (int g = blockIdx.x; g < ngroups; g += gridDim.x) {
        __syncthreads();
        int row0 = g * 32;
        if (in_sm) {
            // slice-major input (K==64): 64 consecutive threads read 1 KB
            // contiguous per slice (rows are 32 B apart within a slice).
            for (int cid = t; cid < 4 * K; cid += 256) {
                int slice = cid >> 6, i = cid & 63;
                int rr = i >> 1, half = i & 1;
                int r = row0 + rr;
                u32x4 val = {0u, 0u, 0u, 0u};
                if (r < N_NODES)
                    val = ((const u32x4*)x)[((size_t)slice * N_NODES + row0) * 2 + i];
                *reinterpret_cast<u32x4*>(&xs[rr][slice * 16 + half * 8]) = val;
            }
        } else {
            for (int cid = t; cid < 4 * K; cid += 256) {
                int rr = cid / (K / 8), c8 = cid % (K / 8);
                int r = row0 + rr;
                u32x4 val = {0u, 0u, 0u, 0u};
                if (r < N_NODES) {
                    size_t base = (size_t)r * K + c8 * 8;
                    if (xF32) {
                        const u32x4* xp = (const u32x4*)x;
                        u32x4 q0 = xp[base / 4];
                        u32x4 q1 = xp[base / 4 + 1];
                        val.x = f2bf(__uint_as_float(q0.x)) | ((unsigned int)f2bf(__uint_as_float(q0.y)) << 16);
                        val.y = f2bf(__uint_as_float(q0.z)) | ((unsigned int)f2bf(__uint_as_float(q0.w)) << 16);
                        val.z = f2bf(__uint_as_float(q1.x)) | ((unsigned int)f2bf(__uint_as_float(q1.y)) << 16);
                        val.w = f2bf(__uint_as_float(q1.z)) | ((unsigned int)f2bf(__uint_as_float(q1.w)) << 16);
                    } else {
                        val = ((const u32x4*)x)[base / 8];
                    }
                }
                *reinterpret_cast<u32x4*>(&xs[rr][c8 * 8]) = val;
            }
        }
        __syncthreads();

        f32x4 acc0 = {0.f, 0.f, 0.f, 0.f};
        f32x4 acc1 = {0.f, 0.f, 0.f, 0.f};
#pragma unroll
        for (int c = 0; c < K / 32; ++c) {
            bf16x8 a0 = *reinterpret_cast<bf16x8*>(&xs[l16][c * 32 + quad * 8]);
            bf16x8 a1 = *reinterpret_cast<bf16x8*>(&xs[16 + l16][c * 32 + quad * 8]);
            acc0 = __builtin_amdgcn_mfma_f32_16x16x32_bf16(a0, bfrag[c], acc0, 0, 0, 0);
            acc1 = __builtin_amdgcn_mfma_f32_16x16x32_bf16(a1, bfrag[c], acc1, 0, 0, 0);
        }
        // col = wave*16 + l16 -> slice = wave, within-slice feat = l16
        unsigned short* ow = out + (size_t)wave * (N_NODES * 16);
#pragma unroll
        for (int reg = 0; reg < 4; ++reg) {
            int r0 = row0 + quad * 4 + reg;
            if (r0 < N_NODES) ow[(size_t)r0 * 16 + l16] = f2bf(acc0[reg] * dis[r0]);
            int r1 = row0 + 16 + quad * 4 + reg;
            if (r1 < N_NODES) ow[(size_t)r1 * 16 + l16] = f2bf(acc1[reg] * dis[r1]);
        }
    }
}

// ---------------- CSR shuffle-reduce gather, slice-major (atomic-free) --------
// R2 post-mortem: LDS FP atomics lane-serialize (~4cy/lane, 682us) regardless of
// atomicAdd flavor -> back to round-0's proven shfl-reduce CSR gather, but on
// the slice-major layout (32-B rows, 3.2 MB/slice L2-resident) with XCD
// affinity: xcd = blk&7, slice = xcd>>1, grp = (blk>>3)*2+(xcd&1).
// Block = 4 waves x 1 slice; wave handles 16 nodes; lane = edge-slot(8) x u32-feat(8).
__global__ __launch_bounds__(256) void k_gather_sm(const int* __restrict__ rp,
                                                   const int* __restrict__ csr,
                                                   const float* __restrict__ dis,
                                                   const unsigned short* __restrict__ xws,
                                                   const void* __restrict__ bias,
                                                   unsigned short* __restrict__ out,
                                                   int do_relu,
                                                   const int* __restrict__ flags) {
    int F32 = flags[0];
    int blk = blockIdx.x;
    int xcd = blk & 7;
    int s = xcd >> 1;                              // slice 0..3
    int grp = ((blk >> 3) << 1) | (xcd & 1);       // 64-node group
    int wave = threadIdx.x >> 6, lane = threadIdx.x & 63;
    int nsub = lane >> 3, k = lane & 7;
    const unsigned int* xs = (const unsigned int*)(xws + (size_t)s * N_NODES * 16); // u32 = 2 feats
    unsigned int* op = (unsigned int*)out + (size_t)s * N_NODES * 8;
    float b0 = loadf(bias, s * 16 + 2 * k, F32);
    float b1 = loadf(bias, s * 16 + 2 * k + 1, F32);
    int node0 = grp * 64 + wave * 16;

    for (int ni = 0; ni < 16; ++ni) {
        int node = node0 + ni;
        if (node >= N_NODES) break;
        int start = rp[node], end = rp[node + 1];
        float a0 = 0.f, a1 = 0.f;
        int j = start + nsub;
        if (j < end) {
            int src = csr[j];
            for (;;) {
                int jn = j + 8;
                int sn = (jn < end) ? csr[jn] : 0;   // prefetch next index
                unsigned int v = xs[(size_t)src * 8 + k];
                a0 += bf2f(v & 0xFFFFu);
                a1 += bf2f(v >> 16);
                if (jn >= end) break;
                j = jn; src = sn;
            }
        }
        a0 += __shfl_down(a0, 32, 64); a1 += __shfl_down(a1, 32, 64);
        a0 += __shfl_down(a0, 16, 64); a1 += __shfl_down(a1, 16, 64);
        a0 += __shfl_down(a0, 8, 64);  a1 += __shfl_down(a1, 8, 64);
        if (nsub == 0) {
            unsigned int sv = xs[(size_t)node * 8 + k];   // self row (L2-hot)
            float dn = dis[node];
            float v0 = fmaf(a0 + bf2f(sv & 0xFFFFu), dn, b0);
            float v1 = fmaf(a1 + bf2f(sv >> 16),     dn, b1);
            if (do_relu) { v0 = fmaxf(v0, 0.f); v1 = fmaxf(v1, 0.f); }
            op[(size_t)node * 8 + k] = (unsigned int)f2bf(v0) | ((unsigned int)f2bf(v1) << 16);
        }
    }
}

// ---------------- fused mean-pool + linear head (4 graphs/block) --------------
__global__ __launch_bounds__(256) void k_pool_final(const int* __restrict__ gptr,
                             const unsigned short* __restrict__ h,   // slice-major
                             const void* __restrict__ Wl, const void* __restrict__ bl,
                             void* __restrict__ out, const int* __restrict__ flags) {
    int F32 = flags[0];
    int g = blockIdx.x * 4 + (threadIdx.x >> 6);
    int lane = threadIdx.x & 63;
    if (g >= N_GRAPHS) return;
    int s = gptr[g], e = gptr[g + 1];
    size_t hbase = (size_t)(lane >> 4) * N_NODES * 16 + (lane & 15);
    float acc = 0.0f;
    for (int n = s; n < e; ++n) acc += bf2f(h[hbase + (size_t)n * 16]);
    float cnt = fmaxf((float)(e - s), 1.0f);
    float v = (acc / cnt) * loadf(Wl, lane, F32);
#pragma unroll
    for (int o = 32; o > 0; o >>= 1) v += __shfl_down(v, o, 64);
    if (lane == 0) {
        float r = v + loadf(bl, 0, F32);
        if (F32) ((float*)out)[g] = r;
        else     ((__hip_bfloat16*)out)[g] = __float2bfloat16(r);
    }
}

extern "C" void kernel_launch(void* const* d_in, const int* in_sizes, int n_in,
                              void* d_out, int out_size, void* d_ws, size_t ws_size,
                              hipStream_t stream) {
    const void* x     = d_in[0];
    const void* ei    = d_in[1];
    const void* batch = d_in[2];
    const void* W1 = d_in[3];
    const void* b1 = d_in[4];
    const void* W2 = d_in[5];
    const void* b2 = d_in[6];
    const void* W3 = d_in[7];
    const void* b3 = d_in[8];
    const void* Wl = d_in[9];
    const void* bl = d_in[10];

    // workspace layout (~41 MB)
    float* dis   = (float*)d_ws;             // 100352
    int*   cnt   = (int*)(dis + 100352);     // 100352
    int*   rp    = cnt + 100352;             // 100352 (needs 100001)
    int*   csr   = rp + 100352;              // 1600000
    int*   gcnt  = csr + 1600000;            // 1024
    int*   gptr  = gcnt + 1024;              // 1056 (needs 1025)
    int*   partN = gptr + 1056;              // 512
    int*   bcnt  = partN + 512;              // 256
    int*   flags = bcnt + 256;               // 16
    unsigned int* packed = (unsigned int*)(flags + 16);    // NB*BCAP (7.8 MB)
    unsigned short* bufA = (unsigned short*)(packed + (size_t)NB * BCAP);  // bf16 slice-major (12.8 MB)
    unsigned short* bufB = bufA + (size_t)NSLICE * N_NODES * 16;           // bf16 slice-major (12.8 MB)

    const int TB = 256;
    dim3 blk(TB);
    int gN = (N_NODES + TB - 1) / TB;        // 391
    // gather grid: 782 group-pairs x 8 xcd-slots -> grp 0..1563 covers 1563 used
    int gGA = 782 * 8;

    // init: detect + zero small counters
    k_init<<<1, blk, 0, stream>>>((const unsigned int*)x, (const unsigned int*)ei,
                                  flags, gcnt, bcnt);
    // phase A partition (two-pass fat blocks, + batch counts)
    k_part<<<(N_EDGES + EPB - 1) / EPB, blk, 0, stream>>>(ei, batch, bcnt, gcnt, packed, flags);
    // hist: cnt + dis + scan partials
    k_hist<<<NBU, blk, 0, stream>>>(packed, bcnt, cnt, dis, partN);
    // middle scan: partN exclusive + rp[N] + graph scan -> gptr
    k_scan_mid<<<1, 512, 0, stream>>>(partN, gN, rp, N_NODES, gcnt, gptr);
    // p3: rp
    k_scan_p3<<<gN, blk, 0, stream>>>(cnt, partN, rp, N_NODES);
    // phase B: dense csr (sorted by dst)
    k_bucketcsr<<<NBU, 512, 0, stream>>>(packed, bcnt, rp, csr);

    // ---- layer 1 ----
    k_gemm<F_IN><<<1024, blk, 0, stream>>>(x, W1, dis, bufA, flags, -1, 0);
    k_gather_sm<<<gGA, blk, 0, stream>>>(rp, csr, dis, bufA, b1, bufB, 1, flags);
    // ---- layer 2 ----
    k_gemm<HID><<<1024, blk, 0, stream>>>(bufB, W2, dis, bufA, flags, 0, 1);
    k_gather_sm<<<gGA, blk, 0, stream>>>(rp, csr, dis, bufA, b2, bufB, 1, flags);
    // ---- layer 3 ----
    k_gemm<HID><<<1024, blk, 0, stream>>>(bufB, W3, dis, bufA, flags, 0, 1);
    k_gather_sm<<<gGA, blk, 0, stream>>>(rp, csr, dis, bufA, b3, bufB, 0, flags);

    // ---- pool + head ----
    k_pool_final<<<N_GRAPHS / 4, blk, 0, stream>>>(gptr, bufB, Wl, bl, d_out, flags);
}

// Round 4
// 378.655 us; speedup vs baseline: 5.9574x; 1.4952x over previous
//
#include <hip/hip_runtime.h>
#include <hip/hip_bf16.h>

#define N_NODES 100000
#define N_EDGES 1600000
#define F_IN 128
#define HID 64
#define N_GRAPHS 1024

// fine dst-partition: bucket = dst>>9 (512 nodes/bucket)
#define SH 9
#define NBU 196        // buckets used: ceil(100000/512)
#define NB 200         // allocated
#define BCAP 9728      // mean 8192 + 17 sigma
#define EPB 8192       // edges per k_part block (196 blocks exactly)
#define NSLICE 4       // 4 feature slices x 16 feats; slice table = 3.2 MB (fits XCD L2)

typedef __attribute__((ext_vector_type(8))) short bf16x8;
typedef __attribute__((ext_vector_type(4))) float f32x4;
typedef __attribute__((ext_vector_type(4))) unsigned int u32x4;

// ---------------- bf16 bit helpers --------------------------------------------
__device__ __forceinline__ unsigned short f2bf(float f) {
    __hip_bfloat16 h = __float2bfloat16(f);   // RNE
    return *reinterpret_cast<unsigned short*>(&h);
}
__device__ __forceinline__ float bf2f(unsigned int u) {
    return __uint_as_float(u << 16);
}

// ---------------- dual-path load helpers (wire dtype resolved at runtime) -----
__device__ __forceinline__ float loadf(const void* p, size_t i, int f32) {
    if (f32) return ((const float*)p)[i];
    return __bfloat162float(((const __hip_bfloat16*)p)[i]);
}
__device__ __forceinline__ int loadi(const void* p, size_t i, int i64) {
    if (i64) return (int)((const long long*)p)[i];
    return ((const int*)p)[i];
}

// ---------------- init: wire detect + zero small counters ---------------------
__global__ void k_init(const unsigned int* __restrict__ xw_,
                       const unsigned int* __restrict__ ei_,
                       int* __restrict__ flags,
                       int* __restrict__ gcnt, int* __restrict__ bcnt) {
    __shared__ int cnt_f, cnt_i;
    int t = threadIdx.x;
    if (t == 0) { cnt_f = 0; cnt_i = 0; }
    __syncthreads();
    unsigned int w = xw_[t];
    unsigned int e = (w >> 7) & 0xFFu;
    if (e >= 100u && e <= 140u) atomicAdd(&cnt_f, 1);
    unsigned int iw = ei_[2 * t + 1];
    if (iw == 0u) atomicAdd(&cnt_i, 1);
    for (int i = t; i < N_GRAPHS; i += 256) gcnt[i] = 0;
    for (int i = t; i < NB; i += 256) bcnt[i] = 0;
    __syncthreads();
    if (t == 0) {
        flags[0] = (cnt_f < 180) ? 1 : 0;   // 1 => fp32 wire
        flags[1] = (cnt_i >= 128) ? 1 : 0;  // 1 => int64 wire
    }
}

// ---------------- phase A: partition by dst>>9, two-pass fat blocks -----------
__global__ __launch_bounds__(256) void k_part(const void* __restrict__ ei,
                                              const void* __restrict__ batch,
                                              int* __restrict__ bcnt,
                                              int* __restrict__ gcnt,
                                              unsigned int* __restrict__ packed,
                                              const int* __restrict__ flags) {
    int I64 = flags[1];
    __shared__ int hist[NB];
    __shared__ int base[NB];
    __shared__ int ghist[N_GRAPHS];   // 4 KB
    int t = threadIdx.x;
    if (t < NB) hist[t] = 0;
    for (int i = t; i < N_GRAPHS; i += 256) ghist[i] = 0;
    __syncthreads();
    // batch counting: block covers nodes [blk*512, blk*512+512)
    for (int it = 0; it < 2; ++it) {
        int n = blockIdx.x * 512 + it * 256 + t;
        if (n < N_NODES) atomicAdd(&ghist[loadi(batch, n, I64)], 1);
    }
    // edge pass 1: bucket counts
    int e0 = blockIdx.x * EPB;
#pragma unroll 4
    for (int it = 0; it < EPB / 256; ++it) {
        int e = e0 + it * 256 + t;
        if (e < N_EDGES) {
            int d = loadi(ei, (size_t)N_EDGES + e, I64);
            atomicAdd(&hist[d >> SH], 1);
        }
    }
    __syncthreads();
    if (t < NB) {
        base[t] = hist[t] ? atomicAdd(&bcnt[t], hist[t]) : 0;
        hist[t] = 0;   // reuse as pass-2 rank counter
    }
    for (int i = t; i < N_GRAPHS; i += 256)
        if (ghist[i]) atomicAdd(&gcnt[i], ghist[i]);
    __syncthreads();
    // edge pass 2: rank + write
#pragma unroll 4
    for (int it = 0; it < EPB / 256; ++it) {
        int e = e0 + it * 256 + t;
        if (e < N_EDGES) {
            int s = loadi(ei, e, I64);
            int d = loadi(ei, (size_t)N_EDGES + e, I64);
            int b = d >> SH;
            int r = atomicAdd(&hist[b], 1);
            int pos = base[b] + r;
            if (pos < BCAP)
                packed[(size_t)b * BCAP + pos] = ((unsigned int)s << SH) | (unsigned int)(d & 511);
        }
    }
}

// ---------------- hist: in-degree + dis + scan partials (fused) ---------------
__global__ __launch_bounds__(256) void k_hist(const unsigned int* __restrict__ packed,
                                              const int* __restrict__ bcnt,
                                              int* __restrict__ cnt,
                                              float* __restrict__ dis,
                                              int* __restrict__ partN) {
    __shared__ int hist[512];
    int b = blockIdx.x;
    int t = threadIdx.x;
    int n = bcnt[b];
    if (n > BCAP) n = BCAP;
    for (int i = t; i < 512; i += 256) hist[i] = 0;
    __syncthreads();
    const unsigned int* pb = packed + (size_t)b * BCAP;
    for (int i = t; i < n; i += 256)
        atomicAdd(&hist[pb[i] & 511u], 1);
    __syncthreads();
    int nbase = b << SH;
    for (int i = t; i < 512; i += 256) {
        int node = nbase + i;
        if (node < N_NODES) {
            int c = hist[i];
            cnt[node] = c;
            dis[node] = rsqrtf((float)c + 1.0f);
        }
    }
    __syncthreads();
    for (int off = 128; off > 0; off >>= 1) {
        if (t < off) { hist[t] += hist[t + off]; hist[256 + t] += hist[256 + t + off]; }
        __syncthreads();
    }
    if (t == 0) {
        partN[2 * b] = hist[0];
        if (2 * b + 1 < 391) partN[2 * b + 1] = hist[256];
    }
}

// ---------------- middle scan: partN (391) + graph scan (1024), one block -----
__global__ void k_scan_mid(int* __restrict__ partial, int nb,
                           int* __restrict__ rp, int n,
                           const int* __restrict__ gcnt, int* __restrict__ gptr) {
    __shared__ int s[512];
    int t = threadIdx.x;
    int v = (t < nb) ? partial[t] : 0;
    s[t] = v;
    __syncthreads();
    for (int off = 1; off < 512; off <<= 1) {
        int x = (t >= off) ? s[t - off] : 0;
        __syncthreads();
        s[t] += x;
        __syncthreads();
    }
    if (t < nb) partial[t] = s[t] - v;   // exclusive
    if (t == 511) rp[n] = s[511];        // grand total
    __syncthreads();
    int a = gcnt[2 * t], bq = gcnt[2 * t + 1];
    int ps = a + bq;
    s[t] = ps;
    __syncthreads();
    for (int off = 1; off < 512; off <<= 1) {
        int x = (t >= off) ? s[t - off] : 0;
        __syncthreads();
        s[t] += x;
        __syncthreads();
    }
    int excl = s[t] - ps;
    gptr[2 * t] = excl;
    gptr[2 * t + 1] = excl + a;
    if (t == 511) gptr[1024] = s[511];
}

// ---------------- scan p3: per-256-chunk local scan + offset -> rp ------------
__global__ void k_scan_p3(const int* __restrict__ in, const int* __restrict__ partial,
                          int* __restrict__ out, int n) {
    __shared__ int s[256];
    int t = threadIdx.x;
    int i = blockIdx.x * 256 + t;
    int v = (i < n) ? in[i] : 0;
    s[t] = v;
    __syncthreads();
    for (int off = 1; off < 256; off <<= 1) {
        int x = (t >= off) ? s[t - off] : 0;
        __syncthreads();
        s[t] += x;
        __syncthreads();
    }
    if (i < n) out[i] = partial[blockIdx.x] + s[t] - v;
}

// ---------------- phase B: LDS counting-sort, dense csr writes ----------------
__global__ __launch_bounds__(512) void k_bucketcsr(const unsigned int* __restrict__ packed,
                                                   const int* __restrict__ bcnt,
                                                   const int* __restrict__ rp,
                                                   int* __restrict__ csr) {
    __shared__ int offs[512];
    __shared__ int elds[BCAP];    // 38 KB
    int b = blockIdx.x;
    int nbase = b << SH;
    int base = rp[nbase];
    int lim = nbase + 512; if (lim > N_NODES) lim = N_NODES;
    int nedge = rp[lim] - base;
    if (nedge > BCAP) nedge = BCAP;
    for (int i = threadIdx.x; i < 512; i += 512) {
        int node = nbase + i;
        offs[i] = (node < N_NODES) ? (rp[node] - base) : nedge;
    }
    __syncthreads();
    int n = bcnt[b]; if (n > BCAP) n = BCAP;
    const unsigned int* pb = packed + (size_t)b * BCAP;
    for (int i = threadIdx.x; i < n; i += 512) {
        unsigned int p = pb[i];
        int pos = atomicAdd(&offs[p & 511u], 1);
        if (pos < BCAP) elds[pos] = (int)(p >> SH);
    }
    __syncthreads();
    for (int i = threadIdx.x; i < nedge; i += 512)
        csr[base + i] = elds[i];
}

// ---------------- MFMA GEMM: in[N,K] @ W[K,64] -> out slice-major bf16 --------
// out layout: [4 slices][N_NODES][16 feats] bf16: slice s is a contiguous
// 3.2 MB block -> fits a single XCD L2 during aggregation.
template <int K>
__global__ __launch_bounds__(256) void k_gemm(const void* __restrict__ x,
                                              const void* __restrict__ W,
                                              const float* __restrict__ dis,
                                              unsigned short* __restrict__ out,  // bf16 bits
                                              const int* __restrict__ flags,
                                              int x_is_f32, int in_sm) {
    int Wf32 = flags[0];
    int xF32 = (x_is_f32 < 0) ? Wf32 : x_is_f32;
    __shared__ unsigned short Wt[64][K + 8];
    __shared__ unsigned short xs[32][K + 8];
    int t = threadIdx.x;
    int wave = t >> 6, lane = t & 63;
    int quad = lane >> 4, l16 = lane & 15;

    for (int id = t; id < 64 * K; id += 256) {
        int k = id >> 6, n = id & 63;
        Wt[n][k] = f2bf(loadf(W, id, Wf32));
    }
    __syncthreads();

    bf16x8 bfrag[K / 32];
#pragma unroll
    for (int c = 0; c < K / 32; ++c)
        bfrag[c] = *reinterpret_cast<bf16x8*>(&Wt[wave * 16 + l16][c * 32 + quad * 8]);

    const int ngroups = (N_NODES + 31) / 32;
    for (int g = blockIdx.x; g < ngroups; g += gridDim.x) {
        __syncthreads();
        int row0 = g * 32;
        if (in_sm) {
            // slice-major input (K==64): 64 consecutive threads read 1 KB
            // contiguous per slice (rows are 32 B apart within a slice).
            for (int cid = t; cid < 4 * K; cid += 256) {
                int slice = cid >> 6, i = cid & 63;
                int rr = i >> 1, half = i & 1;
                int r = row0 + rr;
                u32x4 val = {0u, 0u, 0u, 0u};
                if (r < N_NODES)
                    val = ((const u32x4*)x)[((size_t)slice * N_NODES + row0) * 2 + i];
                *reinterpret_cast<u32x4*>(&xs[rr][slice * 16 + half * 8]) = val;
            }
        } else {
            for (int cid = t; cid < 4 * K; cid += 256) {
                int rr = cid / (K / 8), c8 = cid % (K / 8);
                int r = row0 + rr;
                u32x4 val = {0u, 0u, 0u, 0u};
                if (r < N_NODES) {
                    size_t base = (size_t)r * K + c8 * 8;
                    if (xF32) {
                        const u32x4* xp = (const u32x4*)x;
                        u32x4 q0 = xp[base / 4];
                        u32x4 q1 = xp[base / 4 + 1];
                        val.x = f2bf(__uint_as_float(q0.x)) | ((unsigned int)f2bf(__uint_as_float(q0.y)) << 16);
                        val.y = f2bf(__uint_as_float(q0.z)) | ((unsigned int)f2bf(__uint_as_float(q0.w)) << 16);
                        val.z = f2bf(__uint_as_float(q1.x)) | ((unsigned int)f2bf(__uint_as_float(q1.y)) << 16);
                        val.w = f2bf(__uint_as_float(q1.z)) | ((unsigned int)f2bf(__uint_as_float(q1.w)) << 16);
                    } else {
                        val = ((const u32x4*)x)[base / 8];
                    }
                }
                *reinterpret_cast<u32x4*>(&xs[rr][c8 * 8]) = val;
            }
        }
        __syncthreads();

        f32x4 acc0 = {0.f, 0.f, 0.f, 0.f};
        f32x4 acc1 = {0.f, 0.f, 0.f, 0.f};
#pragma unroll
        for (int c = 0; c < K / 32; ++c) {
            bf16x8 a0 = *reinterpret_cast<bf16x8*>(&xs[l16][c * 32 + quad * 8]);
            bf16x8 a1 = *reinterpret_cast<bf16x8*>(&xs[16 + l16][c * 32 + quad * 8]);
            acc0 = __builtin_amdgcn_mfma_f32_16x16x32_bf16(a0, bfrag[c], acc0, 0, 0, 0);
            acc1 = __builtin_amdgcn_mfma_f32_16x16x32_bf16(a1, bfrag[c], acc1, 0, 0, 0);
        }
        // col = wave*16 + l16 -> slice = wave, within-slice feat = l16
        unsigned short* ow = out + (size_t)wave * (N_NODES * 16);
#pragma unroll
        for (int reg = 0; reg < 4; ++reg) {
            int r0 = row0 + quad * 4 + reg;
            if (r0 < N_NODES) ow[(size_t)r0 * 16 + l16] = f2bf(acc0[reg] * dis[r0]);
            int r1 = row0 + 16 + quad * 4 + reg;
            if (r1 < N_NODES) ow[(size_t)r1 * 16 + l16] = f2bf(acc1[reg] * dis[r1]);
        }
    }
}

// ---------------- CSR shuffle-reduce gather, slice-major, 4 nodes/wave --------
// R3 post-mortem: 8eslot x 8featlane dword loads = 256 B/instr -> 4x instr
// bloat vs round-0 (118 us, VALUBusy 42%). Fix: lane = nodesub(4) x eslot(8)
// x half(2), uint4 (16 B) loads -> 32 edges x 32 B = 1024 B per gather instr
// (round-0 parity) on the L2-resident 3.2 MB slice. Reduction: 3 shfl steps
// (stride 2,4,8) x 8 floats serves 4 nodes; epilogue: 8 lanes, one uint4 per
// (node,half). XCD affinity unchanged: xcd=blk&7, slice=xcd>>1.
__global__ __launch_bounds__(256) void k_gather_sm(const int* __restrict__ rp,
                                                   const int* __restrict__ csr,
                                                   const float* __restrict__ dis,
                                                   const unsigned short* __restrict__ xws,
                                                   const void* __restrict__ bias,
                                                   unsigned short* __restrict__ out,
                                                   int do_relu,
                                                   const int* __restrict__ flags) {
    int F32 = flags[0];
    int blk = blockIdx.x;
    int xcd = blk & 7;
    int s = xcd >> 1;                              // slice 0..3
    int grp = ((blk >> 3) << 1) | (xcd & 1);       // 64-node group
    int wave = threadIdx.x >> 6, lane = threadIdx.x & 63;
    int nodesub = lane >> 4;                       // 0..3
    int eslot = (lane >> 1) & 7;                   // 0..7
    int half = lane & 1;                           // 0..1
    const u32x4* xs4 = (const u32x4*)(xws + (size_t)s * N_NODES * 16);  // row = 2 uint4
    u32x4* op = (u32x4*)out + (size_t)s * N_NODES * 2;
    // per-lane bias: 8 bf16 feats of this (slice, half)
    float bb0 = loadf(bias, s * 16 + half * 8 + 0, F32);
    float bb1 = loadf(bias, s * 16 + half * 8 + 1, F32);
    float bb2 = loadf(bias, s * 16 + half * 8 + 2, F32);
    float bb3 = loadf(bias, s * 16 + half * 8 + 3, F32);
    float bb4 = loadf(bias, s * 16 + half * 8 + 4, F32);
    float bb5 = loadf(bias, s * 16 + half * 8 + 5, F32);
    float bb6 = loadf(bias, s * 16 + half * 8 + 6, F32);
    float bb7 = loadf(bias, s * 16 + half * 8 + 7, F32);
    int wbase = grp * 64 + wave * 16;

    for (int ni = 0; ni < 4; ++ni) {
        int node = wbase + ni * 4 + nodesub;
        int valid = node < N_NODES;
        int start = valid ? rp[node] : 0;
        int end = valid ? rp[node + 1] : 0;
        float a0 = 0.f, a1 = 0.f, a2 = 0.f, a3 = 0.f;
        float a4 = 0.f, a5 = 0.f, a6 = 0.f, a7 = 0.f;
        int j = start + eslot;
        if (j < end) {
            int src = csr[j];
            for (;;) {
                int jn = j + 8;
                int sn = (jn < end) ? csr[jn] : 0;   // prefetch next index
                u32x4 v = xs4[(size_t)src * 2 + half];
                a0 += bf2f(v.x & 0xFFFFu); a1 += bf2f(v.x >> 16);
                a2 += bf2f(v.y & 0xFFFFu); a3 += bf2f(v.y >> 16);
                a4 += bf2f(v.z & 0xFFFFu); a5 += bf2f(v.z >> 16);
                a6 += bf2f(v.w & 0xFFFFu); a7 += bf2f(v.w >> 16);
                if (jn >= end) break;
                j = jn; src = sn;
            }
        }
        // reduce over eslot (lanes stride 2: offsets 2,4,8)
#pragma unroll
        for (int off = 2; off <= 8; off <<= 1) {
            a0 += __shfl_down(a0, off, 64); a1 += __shfl_down(a1, off, 64);
            a2 += __shfl_down(a2, off, 64); a3 += __shfl_down(a3, off, 64);
            a4 += __shfl_down(a4, off, 64); a5 += __shfl_down(a5, off, 64);
            a6 += __shfl_down(a6, off, 64); a7 += __shfl_down(a7, off, 64);
        }
        if (((lane & 14) == 0) && valid) {   // eslot == 0: lanes 0,1,16,17,32,33,48,49
            u32x4 sv = xs4[(size_t)node * 2 + half];   // self row (L2-hot)
            float dn = dis[node];
            float v0 = fmaf(a0 + bf2f(sv.x & 0xFFFFu), dn, bb0);
            float v1 = fmaf(a1 + bf2f(sv.x >> 16),     dn, bb1);
            float v2 = fmaf(a2 + bf2f(sv.y & 0xFFFFu), dn, bb2);
            float v3 = fmaf(a3 + bf2f(sv.y >> 16),     dn, bb3);
            float v4 = fmaf(a4 + bf2f(sv.z & 0xFFFFu), dn, bb4);
            float v5 = fmaf(a5 + bf2f(sv.z >> 16),     dn, bb5);
            float v6 = fmaf(a6 + bf2f(sv.w & 0xFFFFu), dn, bb6);
            float v7 = fmaf(a7 + bf2f(sv.w >> 16),     dn, bb7);
            if (do_relu) {
                v0 = fmaxf(v0, 0.f); v1 = fmaxf(v1, 0.f); v2 = fmaxf(v2, 0.f); v3 = fmaxf(v3, 0.f);
                v4 = fmaxf(v4, 0.f); v5 = fmaxf(v5, 0.f); v6 = fmaxf(v6, 0.f); v7 = fmaxf(v7, 0.f);
            }
            u32x4 o;
            o.x = (unsigned int)f2bf(v0) | ((unsigned int)f2bf(v1) << 16);
            o.y = (unsigned int)f2bf(v2) | ((unsigned int)f2bf(v3) << 16);
            o.z = (unsigned int)f2bf(v4) | ((unsigned int)f2bf(v5) << 16);
            o.w = (unsigned int)f2bf(v6) | ((unsigned int)f2bf(v7) << 16);
            op[(size_t)node * 2 + half] = o;
        }
    }
}

// ---------------- fused mean-pool + linear head (4 graphs/block) --------------
__global__ __launch_bounds__(256) void k_pool_final(const int* __restrict__ gptr,
                             const unsigned short* __restrict__ h,   // slice-major
                             const void* __restrict__ Wl, const void* __restrict__ bl,
                             void* __restrict__ out, const int* __restrict__ flags) {
    int F32 = flags[0];
    int g = blockIdx.x * 4 + (threadIdx.x >> 6);
    int lane = threadIdx.x & 63;
    if (g >= N_GRAPHS) return;
    int s = gptr[g], e = gptr[g + 1];
    size_t hbase = (size_t)(lane >> 4) * N_NODES * 16 + (lane & 15);
    float acc = 0.0f;
    for (int n = s; n < e; ++n) acc += bf2f(h[hbase + (size_t)n * 16]);
    float cnt = fmaxf((float)(e - s), 1.0f);
    float v = (acc / cnt) * loadf(Wl, lane, F32);
#pragma unroll
    for (int o = 32; o > 0; o >>= 1) v += __shfl_down(v, o, 64);
    if (lane == 0) {
        float r = v + loadf(bl, 0, F32);
        if (F32) ((float*)out)[g] = r;
        else     ((__hip_bfloat16*)out)[g] = __float2bfloat16(r);
    }
}

extern "C" void kernel_launch(void* const* d_in, const int* in_sizes, int n_in,
                              void* d_out, int out_size, void* d_ws, size_t ws_size,
                              hipStream_t stream) {
    const void* x     = d_in[0];
    const void* ei    = d_in[1];
    const void* batch = d_in[2];
    const void* W1 = d_in[3];
    const void* b1 = d_in[4];
    const void* W2 = d_in[5];
    const void* b2 = d_in[6];
    const void* W3 = d_in[7];
    const void* b3 = d_in[8];
    const void* Wl = d_in[9];
    const void* bl = d_in[10];

    // workspace layout (~41 MB)
    float* dis   = (float*)d_ws;             // 100352
    int*   cnt   = (int*)(dis + 100352);     // 100352
    int*   rp    = cnt + 100352;             // 100352 (needs 100001)
    int*   csr   = rp + 100352;              // 1600000
    int*   gcnt  = csr + 1600000;            // 1024
    int*   gptr  = gcnt + 1024;              // 1056 (needs 1025)
    int*   partN = gptr + 1056;              // 512
    int*   bcnt  = partN + 512;              // 256
    int*   flags = bcnt + 256;               // 16
    unsigned int* packed = (unsigned int*)(flags + 16);    // NB*BCAP (7.8 MB)
    unsigned short* bufA = (unsigned short*)(packed + (size_t)NB * BCAP);  // bf16 slice-major (12.8 MB)
    unsigned short* bufB = bufA + (size_t)NSLICE * N_NODES * 16;           // bf16 slice-major (12.8 MB)

    const int TB = 256;
    dim3 blk(TB);
    int gN = (N_NODES + TB - 1) / TB;        // 391
    // gather grid: 782 group-pairs x 8 xcd-slots -> grp 0..1563 covers 100032 nodes
    int gGA = 782 * 8;

    // init: detect + zero small counters
    k_init<<<1, blk, 0, stream>>>((const unsigned int*)x, (const unsigned int*)ei,
                                  flags, gcnt, bcnt);
    // phase A partition (two-pass fat blocks, + batch counts)
    k_part<<<(N_EDGES + EPB - 1) / EPB, blk, 0, stream>>>(ei, batch, bcnt, gcnt, packed, flags);
    // hist: cnt + dis + scan partials
    k_hist<<<NBU, blk, 0, stream>>>(packed, bcnt, cnt, dis, partN);
    // middle scan: partN exclusive + rp[N] + graph scan -> gptr
    k_scan_mid<<<1, 512, 0, stream>>>(partN, gN, rp, N_NODES, gcnt, gptr);
    // p3: rp
    k_scan_p3<<<gN, blk, 0, stream>>>(cnt, partN, rp, N_NODES);
    // phase B: dense csr (sorted by dst)
    k_bucketcsr<<<NBU, 512, 0, stream>>>(packed, bcnt, rp, csr);

    // ---- layer 1 ----
    k_gemm<F_IN><<<1024, blk, 0, stream>>>(x, W1, dis, bufA, flags, -1, 0);
    k_gather_sm<<<gGA, blk, 0, stream>>>(rp, csr, dis, bufA, b1, bufB, 1, flags);
    // ---- layer 2 ----
    k_gemm<HID><<<1024, blk, 0, stream>>>(bufB, W2, dis, bufA, flags, 0, 1);
    k_gather_sm<<<gGA, blk, 0, stream>>>(rp, csr, dis, bufA, b2, bufB, 1, flags);
    // ---- layer 3 ----
    k_gemm<HID><<<1024, blk, 0, stream>>>(bufB, W3, dis, bufA, flags, 0, 1);
    k_gather_sm<<<gGA, blk, 0, stream>>>(rp, csr, dis, bufA, b3, bufB, 0, flags);

    // ---- pool + head ----
    k_pool_final<<<N_GRAPHS / 4, blk, 0, stream>>>(gptr, bufB, Wl, bl, d_out, flags);
}

// Round 5
// 361.739 us; speedup vs baseline: 6.2360x; 1.0468x over previous
//
#include <hip/hip_runtime.h>
#include <hip/hip_bf16.h>

#define N_NODES 100000
#define N_EDGES 1600000
#define F_IN 128
#define HID 64
#define N_GRAPHS 1024

// fine dst-partition: bucket = dst>>9 (512 nodes/bucket)
#define SH 9
#define NBU 196        // buckets used: ceil(100000/512)
#define NB 200         // allocated
#define BCAP 9728      // mean 8192 + 17 sigma
#define EPB 8192       // edges per k_part block (196 blocks exactly)
#define NSLICE 4       // 4 feature slices x 16 feats; slice table = 3.2 MB (fits XCD L2)

typedef __attribute__((ext_vector_type(8))) short bf16x8;
typedef __attribute__((ext_vector_type(4))) float f32x4;
typedef __attribute__((ext_vector_type(4))) unsigned int u32x4;

// ---------------- bf16 bit helpers --------------------------------------------
__device__ __forceinline__ unsigned short f2bf(float f) {
    __hip_bfloat16 h = __float2bfloat16(f);   // RNE
    return *reinterpret_cast<unsigned short*>(&h);
}
__device__ __forceinline__ float bf2f(unsigned int u) {
    return __uint_as_float(u << 16);
}

// ---------------- dual-path load helpers (wire dtype resolved at runtime) -----
__device__ __forceinline__ float loadf(const void* p, size_t i, int f32) {
    if (f32) return ((const float*)p)[i];
    return __bfloat162float(((const __hip_bfloat16*)p)[i]);
}
__device__ __forceinline__ int loadi(const void* p, size_t i, int i64) {
    if (i64) return (int)((const long long*)p)[i];
    return ((const int*)p)[i];
}

// ---------------- init: wire detect + zero small counters ---------------------
__global__ void k_init(const unsigned int* __restrict__ xw_,
                       const unsigned int* __restrict__ ei_,
                       int* __restrict__ flags,
                       int* __restrict__ gcnt, int* __restrict__ bcnt) {
    __shared__ int cnt_f, cnt_i;
    int t = threadIdx.x;
    if (t == 0) { cnt_f = 0; cnt_i = 0; }
    __syncthreads();
    unsigned int w = xw_[t];
    unsigned int e = (w >> 7) & 0xFFu;
    if (e >= 100u && e <= 140u) atomicAdd(&cnt_f, 1);
    unsigned int iw = ei_[2 * t + 1];
    if (iw == 0u) atomicAdd(&cnt_i, 1);
    for (int i = t; i < N_GRAPHS; i += 256) gcnt[i] = 0;
    for (int i = t; i < NB; i += 256) bcnt[i] = 0;
    __syncthreads();
    if (t == 0) {
        flags[0] = (cnt_f < 180) ? 1 : 0;   // 1 => fp32 wire
        flags[1] = (cnt_i >= 128) ? 1 : 0;  // 1 => int64 wire
    }
}

// ---------------- phase A: partition by dst>>9, two-pass fat blocks -----------
// R4: pass 1 stages packed word + bucket id in LDS; pass 2 re-reads LDS instead
// of re-reading edge_index from global (-12.8 MB int64 traffic, -1.6M decodes).
__global__ __launch_bounds__(256) void k_part(const void* __restrict__ ei,
                                              const void* __restrict__ batch,
                                              int* __restrict__ bcnt,
                                              int* __restrict__ gcnt,
                                              unsigned int* __restrict__ packed,
                                              const int* __restrict__ flags) {
    int I64 = flags[1];
    __shared__ int hist[NB];
    __shared__ int base[NB];
    __shared__ int ghist[N_GRAPHS];        // 4 KB
    __shared__ unsigned int elds[EPB];     // 32 KB: packed words
    __shared__ unsigned char ebkt[EPB];    // 8 KB: bucket ids (0xFF = invalid)
    int t = threadIdx.x;
    if (t < NB) hist[t] = 0;
    for (int i = t; i < N_GRAPHS; i += 256) ghist[i] = 0;
    __syncthreads();
    // batch counting: block covers nodes [blk*512, blk*512+512)
    for (int it = 0; it < 2; ++it) {
        int n = blockIdx.x * 512 + it * 256 + t;
        if (n < N_NODES) atomicAdd(&ghist[loadi(batch, n, I64)], 1);
    }
    // edge pass 1: decode once, stage in LDS, bucket counts
    int e0 = blockIdx.x * EPB;
#pragma unroll 4
    for (int it = 0; it < EPB / 256; ++it) {
        int idx = it * 256 + t;
        int e = e0 + idx;
        unsigned int pv = 0u;
        unsigned char bk = 0xFFu;
        if (e < N_EDGES) {
            int sN = loadi(ei, e, I64);
            int d = loadi(ei, (size_t)N_EDGES + e, I64);
            bk = (unsigned char)(d >> SH);
            pv = ((unsigned int)sN << SH) | (unsigned int)(d & 511);
            atomicAdd(&hist[d >> SH], 1);
        }
        elds[idx] = pv;
        ebkt[idx] = bk;
    }
    __syncthreads();
    if (t < NB) {
        base[t] = hist[t] ? atomicAdd(&bcnt[t], hist[t]) : 0;
        hist[t] = 0;   // reuse as pass-2 rank counter
    }
    for (int i = t; i < N_GRAPHS; i += 256)
        if (ghist[i]) atomicAdd(&gcnt[i], ghist[i]);
    __syncthreads();
    // edge pass 2: rank + write from LDS
#pragma unroll 4
    for (int it = 0; it < EPB / 256; ++it) {
        int idx = it * 256 + t;
        unsigned char bk = ebkt[idx];
        if (bk != 0xFFu) {
            unsigned int pv = elds[idx];
            int r = atomicAdd(&hist[bk], 1);
            int pos = base[bk] + r;
            if (pos < BCAP)
                packed[(size_t)bk * BCAP + pos] = pv;
        }
    }
}

// ---------------- hist: in-degree + dis + scan partials (fused) ---------------
__global__ __launch_bounds__(256) void k_hist(const unsigned int* __restrict__ packed,
                                              const int* __restrict__ bcnt,
                                              int* __restrict__ cnt,
                                              float* __restrict__ dis,
                                              int* __restrict__ partN) {
    __shared__ int hist[512];
    int b = blockIdx.x;
    int t = threadIdx.x;
    int n = bcnt[b];
    if (n > BCAP) n = BCAP;
    for (int i = t; i < 512; i += 256) hist[i] = 0;
    __syncthreads();
    const unsigned int* pb = packed + (size_t)b * BCAP;
    for (int i = t; i < n; i += 256)
        atomicAdd(&hist[pb[i] & 511u], 1);
    __syncthreads();
    int nbase = b << SH;
    for (int i = t; i < 512; i += 256) {
        int node = nbase + i;
        if (node < N_NODES) {
            int c = hist[i];
            cnt[node] = c;
            dis[node] = rsqrtf((float)c + 1.0f);
        }
    }
    __syncthreads();
    for (int off = 128; off > 0; off >>= 1) {
        if (t < off) { hist[t] += hist[t + off]; hist[256 + t] += hist[256 + t + off]; }
        __syncthreads();
    }
    if (t == 0) {
        partN[2 * b] = hist[0];
        if (2 * b + 1 < 391) partN[2 * b + 1] = hist[256];
    }
}

// ---------------- middle scan: partN (391) + graph scan (1024), one block -----
__global__ void k_scan_mid(int* __restrict__ partial, int nb,
                           int* __restrict__ rp, int n,
                           const int* __restrict__ gcnt, int* __restrict__ gptr) {
    __shared__ int s[512];
    int t = threadIdx.x;
    int v = (t < nb) ? partial[t] : 0;
    s[t] = v;
    __syncthreads();
    for (int off = 1; off < 512; off <<= 1) {
        int x = (t >= off) ? s[t - off] : 0;
        __syncthreads();
        s[t] += x;
        __syncthreads();
    }
    if (t < nb) partial[t] = s[t] - v;   // exclusive
    if (t == 511) rp[n] = s[511];        // grand total
    __syncthreads();
    int a = gcnt[2 * t], bq = gcnt[2 * t + 1];
    int ps = a + bq;
    s[t] = ps;
    __syncthreads();
    for (int off = 1; off < 512; off <<= 1) {
        int x = (t >= off) ? s[t - off] : 0;
        __syncthreads();
        s[t] += x;
        __syncthreads();
    }
    int excl = s[t] - ps;
    gptr[2 * t] = excl;
    gptr[2 * t + 1] = excl + a;
    if (t == 511) gptr[1024] = s[511];
}

// ---------------- scan p3: per-256-chunk local scan + offset -> rp ------------
__global__ void k_scan_p3(const int* __restrict__ in, const int* __restrict__ partial,
                          int* __restrict__ out, int n) {
    __shared__ int s[256];
    int t = threadIdx.x;
    int i = blockIdx.x * 256 + t;
    int v = (i < n) ? in[i] : 0;
    s[t] = v;
    __syncthreads();
    for (int off = 1; off < 256; off <<= 1) {
        int x = (t >= off) ? s[t - off] : 0;
        __syncthreads();
        s[t] += x;
        __syncthreads();
    }
    if (i < n) out[i] = partial[blockIdx.x] + s[t] - v;
}

// ---------------- phase B: LDS counting-sort, dense csr writes ----------------
__global__ __launch_bounds__(512) void k_bucketcsr(const unsigned int* __restrict__ packed,
                                                   const int* __restrict__ bcnt,
                                                   const int* __restrict__ rp,
                                                   int* __restrict__ csr) {
    __shared__ int offs[512];
    __shared__ int elds[BCAP];    // 38 KB
    int b = blockIdx.x;
    int nbase = b << SH;
    int base = rp[nbase];
    int lim = nbase + 512; if (lim > N_NODES) lim = N_NODES;
    int nedge = rp[lim] - base;
    if (nedge > BCAP) nedge = BCAP;
    for (int i = threadIdx.x; i < 512; i += 512) {
        int node = nbase + i;
        offs[i] = (node < N_NODES) ? (rp[node] - base) : nedge;
    }
    __syncthreads();
    int n = bcnt[b]; if (n > BCAP) n = BCAP;
    const unsigned int* pb = packed + (size_t)b * BCAP;
    for (int i = threadIdx.x; i < n; i += 512) {
        unsigned int p = pb[i];
        int pos = atomicAdd(&offs[p & 511u], 1);
        if (pos < BCAP) elds[pos] = (int)(p >> SH);
    }
    __syncthreads();
    for (int i = threadIdx.x; i < nedge; i += 512)
        csr[base + i] = elds[i];
}

// ---------------- MFMA GEMM: in[N,K] @ W[K,64] -> out slice-major bf16 --------
// out layout: [4 slices][N_NODES][16 feats] bf16: slice s is a contiguous
// 3.2 MB block -> fits a single XCD L2 during aggregation.
template <int K>
__global__ __launch_bounds__(256) void k_gemm(const void* __restrict__ x,
                                              const void* __restrict__ W,
                                              const float* __restrict__ dis,
                                              unsigned short* __restrict__ out,  // bf16 bits
                                              const int* __restrict__ flags,
                                              int x_is_f32, int in_sm) {
    int Wf32 = flags[0];
    int xF32 = (x_is_f32 < 0) ? Wf32 : x_is_f32;
    __shared__ unsigned short Wt[64][K + 8];
    __shared__ unsigned short xs[32][K + 8];
    int t = threadIdx.x;
    int wave = t >> 6, lane = t & 63;
    int quad = lane >> 4, l16 = lane & 15;

    for (int id = t; id < 64 * K; id += 256) {
        int k = id >> 6, n = id & 63;
        Wt[n][k] = f2bf(loadf(W, id, Wf32));
    }
    __syncthreads();

    bf16x8 bfrag[K / 32];
#pragma unroll
    for (int c = 0; c < K / 32; ++c)
        bfrag[c] = *reinterpret_cast<bf16x8*>(&Wt[wave * 16 + l16][c * 32 + quad * 8]);

    const int ngroups = (N_NODES + 31) / 32;
    for (int g = blockIdx.x; g < ngroups; g += gridDim.x) {
        __syncthreads();
        int row0 = g * 32;
        if (in_sm) {
            // slice-major input (K==64): 64 consecutive threads read 1 KB
            // contiguous per slice (rows are 32 B apart within a slice).
            for (int cid = t; cid < 4 * K; cid += 256) {
                int slice = cid >> 6, i = cid & 63;
                int rr = i >> 1, half = i & 1;
                int r = row0 + rr;
                u32x4 val = {0u, 0u, 0u, 0u};
                if (r < N_NODES)
                    val = ((const u32x4*)x)[((size_t)slice * N_NODES + row0) * 2 + i];
                *reinterpret_cast<u32x4*>(&xs[rr][slice * 16 + half * 8]) = val;
            }
        } else {
            for (int cid = t; cid < 4 * K; cid += 256) {
                int rr = cid / (K / 8), c8 = cid % (K / 8);
                int r = row0 + rr;
                u32x4 val = {0u, 0u, 0u, 0u};
                if (r < N_NODES) {
                    size_t base = (size_t)r * K + c8 * 8;
                    if (xF32) {
                        const u32x4* xp = (const u32x4*)x;
                        u32x4 q0 = xp[base / 4];
                        u32x4 q1 = xp[base / 4 + 1];
                        val.x = f2bf(__uint_as_float(q0.x)) | ((unsigned int)f2bf(__uint_as_float(q0.y)) << 16);
                        val.y = f2bf(__uint_as_float(q0.z)) | ((unsigned int)f2bf(__uint_as_float(q0.w)) << 16);
                        val.z = f2bf(__uint_as_float(q1.x)) | ((unsigned int)f2bf(__uint_as_float(q1.y)) << 16);
                        val.w = f2bf(__uint_as_float(q1.z)) | ((unsigned int)f2bf(__uint_as_float(q1.w)) << 16);
                    } else {
                        val = ((const u32x4*)x)[base / 8];
                    }
                }
                *reinterpret_cast<u32x4*>(&xs[rr][c8 * 8]) = val;
            }
        }
        __syncthreads();

        f32x4 acc0 = {0.f, 0.f, 0.f, 0.f};
        f32x4 acc1 = {0.f, 0.f, 0.f, 0.f};
#pragma unroll
        for (int c = 0; c < K / 32; ++c) {
            bf16x8 a0 = *reinterpret_cast<bf16x8*>(&xs[l16][c * 32 + quad * 8]);
            bf16x8 a1 = *reinterpret_cast<bf16x8*>(&xs[16 + l16][c * 32 + quad * 8]);
            acc0 = __builtin_amdgcn_mfma_f32_16x16x32_bf16(a0, bfrag[c], acc0, 0, 0, 0);
            acc1 = __builtin_amdgcn_mfma_f32_16x16x32_bf16(a1, bfrag[c], acc1, 0, 0, 0);
        }
        // col = wave*16 + l16 -> slice = wave, within-slice feat = l16
        unsigned short* ow = out + (size_t)wave * (N_NODES * 16);
#pragma unroll
        for (int reg = 0; reg < 4; ++reg) {
            int r0 = row0 + quad * 4 + reg;
            if (r0 < N_NODES) ow[(size_t)r0 * 16 + l16] = f2bf(acc0[reg] * dis[r0]);
            int r1 = row0 + 16 + quad * 4 + reg;
            if (r1 < N_NODES) ow[(size_t)r1 * 16 + l16] = f2bf(acc1[reg] * dis[r1]);
        }
    }
}

// ---------------- CSR shuffle-reduce gather, slice-major, 4 nodes/wave --------
// R4: 2-deep edge pipeline. Streams a (ja, ja+16, ...) and b (ja+8, ja+24, ...)
// issue two independent uint4 gathers + two csr index loads per iteration ->
// halves the exposed-latency chain per node pack. Lane map unchanged:
// lane = nodesub(4) x eslot(8) x half(2); XCD affinity: xcd=blk&7, slice=xcd>>1.
__global__ __launch_bounds__(256) void k_gather_sm(const int* __restrict__ rp,
                                                   const int* __restrict__ csr,
                                                   const float* __restrict__ dis,
                                                   const unsigned short* __restrict__ xws,
                                                   const void* __restrict__ bias,
                                                   unsigned short* __restrict__ out,
                                                   int do_relu,
                                                   const int* __restrict__ flags) {
    int F32 = flags[0];
    int blk = blockIdx.x;
    int xcd = blk & 7;
    int s = xcd >> 1;                              // slice 0..3
    int grp = ((blk >> 3) << 1) | (xcd & 1);       // 64-node group
    int wave = threadIdx.x >> 6, lane = threadIdx.x & 63;
    int nodesub = lane >> 4;                       // 0..3
    int eslot = (lane >> 1) & 7;                   // 0..7
    int half = lane & 1;                           // 0..1
    const u32x4* xs4 = (const u32x4*)(xws + (size_t)s * N_NODES * 16);  // row = 2 uint4
    u32x4* op = (u32x4*)out + (size_t)s * N_NODES * 2;
    // per-lane bias: 8 bf16 feats of this (slice, half)
    float bb0 = loadf(bias, s * 16 + half * 8 + 0, F32);
    float bb1 = loadf(bias, s * 16 + half * 8 + 1, F32);
    float bb2 = loadf(bias, s * 16 + half * 8 + 2, F32);
    float bb3 = loadf(bias, s * 16 + half * 8 + 3, F32);
    float bb4 = loadf(bias, s * 16 + half * 8 + 4, F32);
    float bb5 = loadf(bias, s * 16 + half * 8 + 5, F32);
    float bb6 = loadf(bias, s * 16 + half * 8 + 6, F32);
    float bb7 = loadf(bias, s * 16 + half * 8 + 7, F32);
    int wbase = grp * 64 + wave * 16;

    for (int ni = 0; ni < 4; ++ni) {
        int node = wbase + ni * 4 + nodesub;
        int valid = node < N_NODES;
        int start = valid ? rp[node] : 0;
        int end = valid ? rp[node + 1] : 0;
        float a0 = 0.f, a1 = 0.f, a2 = 0.f, a3 = 0.f;
        float a4 = 0.f, a5 = 0.f, a6 = 0.f, a7 = 0.f;
        int ja = start + eslot;
        if (ja < end) {
            int jb = ja + 8;
            int sa = csr[ja];
            int okb = (jb < end);
            int sb = okb ? csr[jb] : sa;           // !okb: re-load sa's line (L1-hot)
            for (;;) {
                u32x4 va = xs4[(size_t)sa * 2 + half];
                u32x4 vb = xs4[(size_t)sb * 2 + half];
                int jan = ja + 16, jbn = jb + 16;
                int san = (jan < end) ? csr[jan] : 0;
                int sbn = (jbn < end) ? csr[jbn] : 0;
                a0 += bf2f(va.x & 0xFFFFu); a1 += bf2f(va.x >> 16);
                a2 += bf2f(va.y & 0xFFFFu); a3 += bf2f(va.y >> 16);
                a4 += bf2f(va.z & 0xFFFFu); a5 += bf2f(va.z >> 16);
                a6 += bf2f(va.w & 0xFFFFu); a7 += bf2f(va.w >> 16);
                if (okb) {
                    a0 += bf2f(vb.x & 0xFFFFu); a1 += bf2f(vb.x >> 16);
                    a2 += bf2f(vb.y & 0xFFFFu); a3 += bf2f(vb.y >> 16);
                    a4 += bf2f(vb.z & 0xFFFFu); a5 += bf2f(vb.z >> 16);
                    a6 += bf2f(vb.w & 0xFFFFu); a7 += bf2f(vb.w >> 16);
                }
                if (jan >= end) break;
                ja = jan; jb = jbn; sa = san; sb = sbn;
                okb = (jbn < end);
            }
        }
        // reduce over eslot (lanes stride 2: offsets 2,4,8)
#pragma unroll
        for (int off = 2; off <= 8; off <<= 1) {
            a0 += __shfl_down(a0, off, 64); a1 += __shfl_down(a1, off, 64);
            a2 += __shfl_down(a2, off, 64); a3 += __shfl_down(a3, off, 64);
            a4 += __shfl_down(a4, off, 64); a5 += __shfl_down(a5, off, 64);
            a6 += __shfl_down(a6, off, 64); a7 += __shfl_down(a7, off, 64);
        }
        if (((lane & 14) == 0) && valid) {   // eslot == 0: lanes 0,1,16,17,32,33,48,49
            u32x4 sv = xs4[(size_t)node * 2 + half];   // self row (L2-hot)
            float dn = dis[node];
            float v0 = fmaf(a0 + bf2f(sv.x & 0xFFFFu), dn, bb0);
            float v1 = fmaf(a1 + bf2f(sv.x >> 16),     dn, bb1);
            float v2 = fmaf(a2 + bf2f(sv.y & 0xFFFFu), dn, bb2);
            float v3 = fmaf(a3 + bf2f(sv.y >> 16),     dn, bb3);
            float v4 = fmaf(a4 + bf2f(sv.z & 0xFFFFu), dn, bb4);
            float v5 = fmaf(a5 + bf2f(sv.z >> 16),     dn, bb5);
            float v6 = fmaf(a6 + bf2f(sv.w & 0xFFFFu), dn, bb6);
            float v7 = fmaf(a7 + bf2f(sv.w >> 16),     dn, bb7);
            if (do_relu) {
                v0 = fmaxf(v0, 0.f); v1 = fmaxf(v1, 0.f); v2 = fmaxf(v2, 0.f); v3 = fmaxf(v3, 0.f);
                v4 = fmaxf(v4, 0.f); v5 = fmaxf(v5, 0.f); v6 = fmaxf(v6, 0.f); v7 = fmaxf(v7, 0.f);
            }
            u32x4 o;
            o.x = (unsigned int)f2bf(v0) | ((unsigned int)f2bf(v1) << 16);
            o.y = (unsigned int)f2bf(v2) | ((unsigned int)f2bf(v3) << 16);
            o.z = (unsigned int)f2bf(v4) | ((unsigned int)f2bf(v5) << 16);
            o.w = (unsigned int)f2bf(v6) | ((unsigned int)f2bf(v7) << 16);
            op[(size_t)node * 2 + half] = o;
        }
    }
}

// ---------------- fused mean-pool + linear head (1 graph/block, coalesced) ----
// R4 rewrite: old version was 1 block/CU with serial 2-B strided loads. Now
// 1024 blocks; wave = slice, lane = nodesub(8) x u32feat(8): each wave-instr
// reads 8 nodes x 32 B contiguous from its slice. shfl-tree over nodes, dot
// with Wl over feats, LDS combine across the 4 slice-waves.
__global__ __launch_bounds__(256) void k_pool_final(const int* __restrict__ gptr,
                             const unsigned short* __restrict__ h,   // slice-major
                             const void* __restrict__ Wl, const void* __restrict__ bl,
                             void* __restrict__ out, const int* __restrict__ flags) {
    int F32 = flags[0];
    __shared__ float part[4];
    int g = blockIdx.x;
    int s = threadIdx.x >> 6;        // slice = wave
    int lane = threadIdx.x & 63;
    int nsub = lane >> 3, up = lane & 7;
    int s0 = gptr[g], e0 = gptr[g + 1];
    const unsigned int* xsl = (const unsigned int*)h + (size_t)s * N_NODES * 8;
    float a0 = 0.f, a1 = 0.f;
    for (int n = s0 + nsub; n < e0; n += 8) {
        unsigned int v = xsl[(size_t)n * 8 + up];
        a0 += bf2f(v & 0xFFFFu);
        a1 += bf2f(v >> 16);
    }
    a0 += __shfl_down(a0, 32, 64); a1 += __shfl_down(a1, 32, 64);
    a0 += __shfl_down(a0, 16, 64); a1 += __shfl_down(a1, 16, 64);
    a0 += __shfl_down(a0, 8, 64);  a1 += __shfl_down(a1, 8, 64);
    float v = 0.f;
    if (nsub == 0) {
        float cnt = fmaxf((float)(e0 - s0), 1.0f);
        int f = s * 16 + up * 2;
        v = (a0 / cnt) * loadf(Wl, f, F32) + (a1 / cnt) * loadf(Wl, f + 1, F32);
    }
    v += __shfl_down(v, 4, 64);
    v += __shfl_down(v, 2, 64);
    v += __shfl_down(v, 1, 64);
    if (lane == 0) part[s] = v;
    __syncthreads();
    if (threadIdx.x == 0) {
        float r = part[0] + part[1] + part[2] + part[3] + loadf(bl, 0, F32);
        if (F32) ((float*)out)[g] = r;
        else     ((__hip_bfloat16*)out)[g] = __float2bfloat16(r);
    }
}

extern "C" void kernel_launch(void* const* d_in, const int* in_sizes, int n_in,
                              void* d_out, int out_size, void* d_ws, size_t ws_size,
                              hipStream_t stream) {
    const void* x     = d_in[0];
    const void* ei    = d_in[1];
    const void* batch = d_in[2];
    const void* W1 = d_in[3];
    const void* b1 = d_in[4];
    const void* W2 = d_in[5];
    const void* b2 = d_in[6];
    const void* W3 = d_in[7];
    const void* b3 = d_in[8];
    const void* Wl = d_in[9];
    const void* bl = d_in[10];

    // workspace layout (~41 MB)
    float* dis   = (float*)d_ws;             // 100352
    int*   cnt   = (int*)(dis + 100352);     // 100352
    int*   rp    = cnt + 100352;             // 100352 (needs 100001)
    int*   csr   = rp + 100352;              // 1600000
    int*   gcnt  = csr + 1600000;            // 1024
    int*   gptr  = gcnt + 1024;              // 1056 (needs 1025)
    int*   partN = gptr + 1056;              // 512
    int*   bcnt  = partN + 512;              // 256
    int*   flags = bcnt + 256;               // 16
    unsigned int* packed = (unsigned int*)(flags + 16);    // NB*BCAP (7.8 MB)
    unsigned short* bufA = (unsigned short*)(packed + (size_t)NB * BCAP);  // bf16 slice-major (12.8 MB)
    unsigned short* bufB = bufA + (size_t)NSLICE * N_NODES * 16;           // bf16 slice-major (12.8 MB)

    const int TB = 256;
    dim3 blk(TB);
    int gN = (N_NODES + TB - 1) / TB;        // 391
    // gather grid: 782 group-pairs x 8 xcd-slots -> grp 0..1563 covers 100096 nodes
    int gGA = 782 * 8;

    // init: detect + zero small counters
    k_init<<<1, blk, 0, stream>>>((const unsigned int*)x, (const unsigned int*)ei,
                                  flags, gcnt, bcnt);
    // phase A partition (two-pass fat blocks with LDS staging, + batch counts)
    k_part<<<(N_EDGES + EPB - 1) / EPB, blk, 0, stream>>>(ei, batch, bcnt, gcnt, packed, flags);
    // hist: cnt + dis + scan partials
    k_hist<<<NBU, blk, 0, stream>>>(packed, bcnt, cnt, dis, partN);
    // middle scan: partN exclusive + rp[N] + graph scan -> gptr
    k_scan_mid<<<1, 512, 0, stream>>>(partN, gN, rp, N_NODES, gcnt, gptr);
    // p3: rp
    k_scan_p3<<<gN, blk, 0, stream>>>(cnt, partN, rp, N_NODES);
    // phase B: dense csr (sorted by dst)
    k_bucketcsr<<<NBU, 512, 0, stream>>>(packed, bcnt, rp, csr);

    // ---- layer 1 ----
    k_gemm<F_IN><<<1024, blk, 0, stream>>>(x, W1, dis, bufA, flags, -1, 0);
    k_gather_sm<<<gGA, blk, 0, stream>>>(rp, csr, dis, bufA, b1, bufB, 1, flags);
    // ---- layer 2 ----
    k_gemm<HID><<<1024, blk, 0, stream>>>(bufB, W2, dis, bufA, flags, 0, 1);
    k_gather_sm<<<gGA, blk, 0, stream>>>(rp, csr, dis, bufA, b2, bufB, 1, flags);
    // ---- layer 3 ----
    k_gemm<HID><<<1024, blk, 0, stream>>>(bufB, W3, dis, bufA, flags, 0, 1);
    k_gather_sm<<<gGA, blk, 0, stream>>>(rp, csr, dis, bufA, b3, bufB, 0, flags);

    // ---- pool + head ----
    k_pool_final<<<N_GRAPHS, blk, 0, stream>>>(gptr, bufB, Wl, bl, d_out, flags);
}

// Round 6
// 350.292 us; speedup vs baseline: 6.4397x; 1.0327x over previous
//
#include <hip/hip_runtime.h>
#include <hip/hip_bf16.h>

#define N_NODES 100000
#define N_EDGES 1600000
#define F_IN 128
#define HID 64
#define N_GRAPHS 1024

// fine dst-partition: bucket = dst>>9 (512 nodes/bucket)
#define SH 9
#define NBU 196        // buckets used: ceil(100000/512)
#define NB 200         // allocated
#define BCAP 9728      // mean 8192 + 17 sigma
#define EPB 8192       // edges per k_part block (196 blocks exactly)
#define NSLICE 4       // 4 feature slices x 16 feats; slice table = 3.2 MB (fits XCD L2)

typedef __attribute__((ext_vector_type(8))) short bf16x8;
typedef __attribute__((ext_vector_type(4))) float f32x4;
typedef __attribute__((ext_vector_type(4))) unsigned int u32x4;

// ---------------- bf16 bit helpers --------------------------------------------
__device__ __forceinline__ unsigned short f2bf(float f) {
    __hip_bfloat16 h = __float2bfloat16(f);   // RNE
    return *reinterpret_cast<unsigned short*>(&h);
}
__device__ __forceinline__ float bf2f(unsigned int u) {
    return __uint_as_float(u << 16);
}

// ---------------- dual-path load helpers (wire dtype resolved at runtime) -----
__device__ __forceinline__ float loadf(const void* p, size_t i, int f32) {
    if (f32) return ((const float*)p)[i];
    return __bfloat162float(((const __hip_bfloat16*)p)[i]);
}
__device__ __forceinline__ int loadi(const void* p, size_t i, int i64) {
    if (i64) return (int)((const long long*)p)[i];
    return ((const int*)p)[i];
}

// ---------------- init: wire detect + zero small counters ---------------------
__global__ void k_init(const unsigned int* __restrict__ xw_,
                       const unsigned int* __restrict__ ei_,
                       int* __restrict__ flags,
                       int* __restrict__ gcnt, int* __restrict__ bcnt) {
    __shared__ int cnt_f, cnt_i;
    int t = threadIdx.x;
    if (t == 0) { cnt_f = 0; cnt_i = 0; }
    __syncthreads();
    unsigned int w = xw_[t];
    unsigned int e = (w >> 7) & 0xFFu;
    if (e >= 100u && e <= 140u) atomicAdd(&cnt_f, 1);
    unsigned int iw = ei_[2 * t + 1];
    if (iw == 0u) atomicAdd(&cnt_i, 1);
    for (int i = t; i < N_GRAPHS; i += 256) gcnt[i] = 0;
    for (int i = t; i < NB; i += 256) bcnt[i] = 0;
    __syncthreads();
    if (t == 0) {
        flags[0] = (cnt_f < 180) ? 1 : 0;   // 1 => fp32 wire
        flags[1] = (cnt_i >= 128) ? 1 : 0;  // 1 => int64 wire
    }
}

// ---------------- phase A: partition by dst>>9, two-pass fat blocks -----------
// R4: pass 1 stages packed word + bucket id in LDS; pass 2 re-reads LDS instead
// of re-reading edge_index from global (-12.8 MB int64 traffic, -1.6M decodes).
__global__ __launch_bounds__(256) void k_part(const void* __restrict__ ei,
                                              const void* __restrict__ batch,
                                              int* __restrict__ bcnt,
                                              int* __restrict__ gcnt,
                                              unsigned int* __restrict__ packed,
                                              const int* __restrict__ flags) {
    int I64 = flags[1];
    __shared__ int hist[NB];
    __shared__ int base[NB];
    __shared__ int ghist[N_GRAPHS];        // 4 KB
    __shared__ unsigned int elds[EPB];     // 32 KB: packed words
    __shared__ unsigned char ebkt[EPB];    // 8 KB: bucket ids (0xFF = invalid)
    int t = threadIdx.x;
    if (t < NB) hist[t] = 0;
    for (int i = t; i < N_GRAPHS; i += 256) ghist[i] = 0;
    __syncthreads();
    // batch counting: block covers nodes [blk*512, blk*512+512)
    for (int it = 0; it < 2; ++it) {
        int n = blockIdx.x * 512 + it * 256 + t;
        if (n < N_NODES) atomicAdd(&ghist[loadi(batch, n, I64)], 1);
    }
    // edge pass 1: decode once, stage in LDS, bucket counts
    int e0 = blockIdx.x * EPB;
#pragma unroll 4
    for (int it = 0; it < EPB / 256; ++it) {
        int idx = it * 256 + t;
        int e = e0 + idx;
        unsigned int pv = 0u;
        unsigned char bk = 0xFFu;
        if (e < N_EDGES) {
            int sN = loadi(ei, e, I64);
            int d = loadi(ei, (size_t)N_EDGES + e, I64);
            bk = (unsigned char)(d >> SH);
            pv = ((unsigned int)sN << SH) | (unsigned int)(d & 511);
            atomicAdd(&hist[d >> SH], 1);
        }
        elds[idx] = pv;
        ebkt[idx] = bk;
    }
    __syncthreads();
    if (t < NB) {
        base[t] = hist[t] ? atomicAdd(&bcnt[t], hist[t]) : 0;
        hist[t] = 0;   // reuse as pass-2 rank counter
    }
    for (int i = t; i < N_GRAPHS; i += 256)
        if (ghist[i]) atomicAdd(&gcnt[i], ghist[i]);
    __syncthreads();
    // edge pass 2: rank + write from LDS
#pragma unroll 4
    for (int it = 0; it < EPB / 256; ++it) {
        int idx = it * 256 + t;
        unsigned char bk = ebkt[idx];
        if (bk != 0xFFu) {
            unsigned int pv = elds[idx];
            int r = atomicAdd(&hist[bk], 1);
            int pos = base[bk] + r;
            if (pos < BCAP)
                packed[(size_t)bk * BCAP + pos] = pv;
        }
    }
}

// ---------------- hist: in-degree + dis + scan partials (fused) ---------------
__global__ __launch_bounds__(256) void k_hist(const unsigned int* __restrict__ packed,
                                              const int* __restrict__ bcnt,
                                              int* __restrict__ cnt,
                                              float* __restrict__ dis,
                                              int* __restrict__ partN) {
    __shared__ int hist[512];
    int b = blockIdx.x;
    int t = threadIdx.x;
    int n = bcnt[b];
    if (n > BCAP) n = BCAP;
    for (int i = t; i < 512; i += 256) hist[i] = 0;
    __syncthreads();
    const unsigned int* pb = packed + (size_t)b * BCAP;
    for (int i = t; i < n; i += 256)
        atomicAdd(&hist[pb[i] & 511u], 1);
    __syncthreads();
    int nbase = b << SH;
    for (int i = t; i < 512; i += 256) {
        int node = nbase + i;
        if (node < N_NODES) {
            int c = hist[i];
            cnt[node] = c;
            dis[node] = rsqrtf((float)c + 1.0f);
        }
    }
    __syncthreads();
    for (int off = 128; off > 0; off >>= 1) {
        if (t < off) { hist[t] += hist[t + off]; hist[256 + t] += hist[256 + t + off]; }
        __syncthreads();
    }
    if (t == 0) {
        partN[2 * b] = hist[0];
        if (2 * b + 1 < 391) partN[2 * b + 1] = hist[256];
    }
}

// ---------------- middle scan: partN (391) + graph scan (1024), one block -----
__global__ void k_scan_mid(int* __restrict__ partial, int nb,
                           int* __restrict__ rp, int n,
                           const int* __restrict__ gcnt, int* __restrict__ gptr) {
    __shared__ int s[512];
    int t = threadIdx.x;
    int v = (t < nb) ? partial[t] : 0;
    s[t] = v;
    __syncthreads();
    for (int off = 1; off < 512; off <<= 1) {
        int x = (t >= off) ? s[t - off] : 0;
        __syncthreads();
        s[t] += x;
        __syncthreads();
    }
    if (t < nb) partial[t] = s[t] - v;   // exclusive
    if (t == 511) rp[n] = s[511];        // grand total
    __syncthreads();
    int a = gcnt[2 * t], bq = gcnt[2 * t + 1];
    int ps = a + bq;
    s[t] = ps;
    __syncthreads();
    for (int off = 1; off < 512; off <<= 1) {
        int x = (t >= off) ? s[t - off] : 0;
        __syncthreads();
        s[t] += x;
        __syncthreads();
    }
    int excl = s[t] - ps;
    gptr[2 * t] = excl;
    gptr[2 * t + 1] = excl + a;
    if (t == 511) gptr[1024] = s[511];
}

// ---------------- scan p3: per-256-chunk local scan + offset -> rp ------------
__global__ void k_scan_p3(const int* __restrict__ in, const int* __restrict__ partial,
                          int* __restrict__ out, int n) {
    __shared__ int s[256];
    int t = threadIdx.x;
    int i = blockIdx.x * 256 + t;
    int v = (i < n) ? in[i] : 0;
    s[t] = v;
    __syncthreads();
    for (int off = 1; off < 256; off <<= 1) {
        int x = (t >= off) ? s[t - off] : 0;
        __syncthreads();
        s[t] += x;
        __syncthreads();
    }
    if (i < n) out[i] = partial[blockIdx.x] + s[t] - v;
}

// ---------------- phase B: LDS counting-sort, dense csr writes ----------------
__global__ __launch_bounds__(512) void k_bucketcsr(const unsigned int* __restrict__ packed,
                                                   const int* __restrict__ bcnt,
                                                   const int* __restrict__ rp,
                                                   int* __restrict__ csr) {
    __shared__ int offs[512];
    __shared__ int elds[BCAP];    // 38 KB
    int b = blockIdx.x;
    int nbase = b << SH;
    int base = rp[nbase];
    int lim = nbase + 512; if (lim > N_NODES) lim = N_NODES;
    int nedge = rp[lim] - base;
    if (nedge > BCAP) nedge = BCAP;
    for (int i = threadIdx.x; i < 512; i += 512) {
        int node = nbase + i;
        offs[i] = (node < N_NODES) ? (rp[node] - base) : nedge;
    }
    __syncthreads();
    int n = bcnt[b]; if (n > BCAP) n = BCAP;
    const unsigned int* pb = packed + (size_t)b * BCAP;
    for (int i = threadIdx.x; i < n; i += 512) {
        unsigned int p = pb[i];
        int pos = atomicAdd(&offs[p & 511u], 1);
        if (pos < BCAP) elds[pos] = (int)(p >> SH);
    }
    __syncthreads();
    for (int i = threadIdx.x; i < nedge; i += 512)
        csr[base + i] = elds[i];
}

// ---------------- MFMA GEMM: in[N,K] @ W[K,64] -> out slice-major bf16 --------
// out layout: [4 slices][N_NODES][16 feats] bf16: slice s is a contiguous
// 3.2 MB block -> fits a single XCD L2 during aggregation.
template <int K>
__global__ __launch_bounds__(256) void k_gemm(const void* __restrict__ x,
                                              const void* __restrict__ W,
                                              const float* __restrict__ dis,
                                              unsigned short* __restrict__ out,  // bf16 bits
                                              const int* __restrict__ flags,
                                              int x_is_f32, int in_sm) {
    int Wf32 = flags[0];
    int xF32 = (x_is_f32 < 0) ? Wf32 : x_is_f32;
    __shared__ unsigned short Wt[64][K + 8];
    __shared__ unsigned short xs[32][K + 8];
    int t = threadIdx.x;
    int wave = t >> 6, lane = t & 63;
    int quad = lane >> 4, l16 = lane & 15;

    for (int id = t; id < 64 * K; id += 256) {
        int k = id >> 6, n = id & 63;
        Wt[n][k] = f2bf(loadf(W, id, Wf32));
    }
    __syncthreads();

    bf16x8 bfrag[K / 32];
#pragma unroll
    for (int c = 0; c < K / 32; ++c)
        bfrag[c] = *reinterpret_cast<bf16x8*>(&Wt[wave * 16 + l16][c * 32 + quad * 8]);

    const int ngroups = (N_NODES + 31) / 32;
    for (int g = blockIdx.x; g < ngroups; g += gridDim.x) {
        __syncthreads();
        int row0 = g * 32;
        if (in_sm) {
            // slice-major input (K==64): 64 consecutive threads read 1 KB
            // contiguous per slice (rows are 32 B apart within a slice).
            for (int cid = t; cid < 4 * K; cid += 256) {
                int slice = cid >> 6, i = cid & 63;
                int rr = i >> 1, half = i & 1;
                int r = row0 + rr;
                u32x4 val = {0u, 0u, 0u, 0u};
                if (r < N_NODES)
                    val = ((const u32x4*)x)[((size_t)slice * N_NODES + row0) * 2 + i];
                *reinterpret_cast<u32x4*>(&xs[rr][slice * 16 + half * 8]) = val;
            }
        } else {
            for (int cid = t; cid < 4 * K; cid += 256) {
                int rr = cid / (K / 8), c8 = cid % (K / 8);
                int r = row0 + rr;
                u32x4 val = {0u, 0u, 0u, 0u};
                if (r < N_NODES) {
                    size_t base = (size_t)r * K + c8 * 8;
                    if (xF32) {
                        const u32x4* xp = (const u32x4*)x;
                        u32x4 q0 = xp[base / 4];
                        u32x4 q1 = xp[base / 4 + 1];
                        val.x = f2bf(__uint_as_float(q0.x)) | ((unsigned int)f2bf(__uint_as_float(q0.y)) << 16);
                        val.y = f2bf(__uint_as_float(q0.z)) | ((unsigned int)f2bf(__uint_as_float(q0.w)) << 16);
                        val.z = f2bf(__uint_as_float(q1.x)) | ((unsigned int)f2bf(__uint_as_float(q1.y)) << 16);
                        val.w = f2bf(__uint_as_float(q1.z)) | ((unsigned int)f2bf(__uint_as_float(q1.w)) << 16);
                    } else {
                        val = ((const u32x4*)x)[base / 8];
                    }
                }
                *reinterpret_cast<u32x4*>(&xs[rr][c8 * 8]) = val;
            }
        }
        __syncthreads();

        f32x4 acc0 = {0.f, 0.f, 0.f, 0.f};
        f32x4 acc1 = {0.f, 0.f, 0.f, 0.f};
#pragma unroll
        for (int c = 0; c < K / 32; ++c) {
            bf16x8 a0 = *reinterpret_cast<bf16x8*>(&xs[l16][c * 32 + quad * 8]);
            bf16x8 a1 = *reinterpret_cast<bf16x8*>(&xs[16 + l16][c * 32 + quad * 8]);
            acc0 = __builtin_amdgcn_mfma_f32_16x16x32_bf16(a0, bfrag[c], acc0, 0, 0, 0);
            acc1 = __builtin_amdgcn_mfma_f32_16x16x32_bf16(a1, bfrag[c], acc1, 0, 0, 0);
        }
        // col = wave*16 + l16 -> slice = wave, within-slice feat = l16
        unsigned short* ow = out + (size_t)wave * (N_NODES * 16);
#pragma unroll
        for (int reg = 0; reg < 4; ++reg) {
            int r0 = row0 + quad * 4 + reg;
            if (r0 < N_NODES) ow[(size_t)r0 * 16 + l16] = f2bf(acc0[reg] * dis[r0]);
            int r1 = row0 + 16 + quad * 4 + reg;
            if (r1 < N_NODES) ow[(size_t)r1 * 16 + l16] = f2bf(acc1[reg] * dis[r1]);
        }
    }
}

// ---------------- CSR shuffle-reduce gather, slice-major, 8 nodes/pack --------
// R5 post-mortem: 2-deep pipeline regressed (latency already TLP-hidden); the
// hidden cost was the shfl tree (ds_bpermute on the LDS pipe, 6 shfl/node).
// New lane map: lane = nodesub(8) x eslot(4) x half(2), uint4 loads (still
// 1024 B/gather instr). Reduction: 2 shfl levels serving 8 nodes -> 2
// shfl/node (3x fewer). Single-stream prefetch loop (round-4 style).
// XCD affinity unchanged: xcd=blk&7, slice=xcd>>1.
__global__ __launch_bounds__(256) void k_gather_sm(const int* __restrict__ rp,
                                                   const int* __restrict__ csr,
                                                   const float* __restrict__ dis,
                                                   const unsigned short* __restrict__ xws,
                                                   const void* __restrict__ bias,
                                                   unsigned short* __restrict__ out,
                                                   int do_relu,
                                                   const int* __restrict__ flags) {
    int F32 = flags[0];
    int blk = blockIdx.x;
    int xcd = blk & 7;
    int s = xcd >> 1;                              // slice 0..3
    int grp = ((blk >> 3) << 1) | (xcd & 1);       // 64-node group
    int wave = threadIdx.x >> 6, lane = threadIdx.x & 63;
    int nodesub = lane >> 3;                       // 0..7
    int eslot = (lane >> 1) & 3;                   // 0..3
    int half = lane & 1;                           // 0..1
    const u32x4* xs4 = (const u32x4*)(xws + (size_t)s * N_NODES * 16);  // row = 2 uint4
    u32x4* op = (u32x4*)out + (size_t)s * N_NODES * 2;
    // per-lane bias: 8 bf16 feats of this (slice, half)
    float bb0 = loadf(bias, s * 16 + half * 8 + 0, F32);
    float bb1 = loadf(bias, s * 16 + half * 8 + 1, F32);
    float bb2 = loadf(bias, s * 16 + half * 8 + 2, F32);
    float bb3 = loadf(bias, s * 16 + half * 8 + 3, F32);
    float bb4 = loadf(bias, s * 16 + half * 8 + 4, F32);
    float bb5 = loadf(bias, s * 16 + half * 8 + 5, F32);
    float bb6 = loadf(bias, s * 16 + half * 8 + 6, F32);
    float bb7 = loadf(bias, s * 16 + half * 8 + 7, F32);
    int wbase = grp * 64 + wave * 16;

    for (int ni = 0; ni < 2; ++ni) {
        int node = wbase + ni * 8 + nodesub;
        int valid = node < N_NODES;
        int start = valid ? rp[node] : 0;
        int end = valid ? rp[node + 1] : 0;
        float a0 = 0.f, a1 = 0.f, a2 = 0.f, a3 = 0.f;
        float a4 = 0.f, a5 = 0.f, a6 = 0.f, a7 = 0.f;
        int j = start + eslot;
        if (j < end) {
            int src = csr[j];
            for (;;) {
                int jn = j + 4;
                int sn = (jn < end) ? csr[jn] : 0;   // prefetch next index
                u32x4 v = xs4[(size_t)src * 2 + half];
                a0 += bf2f(v.x & 0xFFFFu); a1 += bf2f(v.x >> 16);
                a2 += bf2f(v.y & 0xFFFFu); a3 += bf2f(v.y >> 16);
                a4 += bf2f(v.z & 0xFFFFu); a5 += bf2f(v.z >> 16);
                a6 += bf2f(v.w & 0xFFFFu); a7 += bf2f(v.w >> 16);
                if (jn >= end) break;
                j = jn; src = sn;
            }
        }
        // reduce over eslot (stride 2: offsets 2, 4)
#pragma unroll
        for (int off = 2; off <= 4; off <<= 1) {
            a0 += __shfl_down(a0, off, 64); a1 += __shfl_down(a1, off, 64);
            a2 += __shfl_down(a2, off, 64); a3 += __shfl_down(a3, off, 64);
            a4 += __shfl_down(a4, off, 64); a5 += __shfl_down(a5, off, 64);
            a6 += __shfl_down(a6, off, 64); a7 += __shfl_down(a7, off, 64);
        }
        if (((lane & 6) == 0) && valid) {   // eslot == 0: 16 lanes (8 nodes x 2 halves)
            u32x4 sv = xs4[(size_t)node * 2 + half];   // self row (L2-hot)
            float dn = dis[node];
            float v0 = fmaf(a0 + bf2f(sv.x & 0xFFFFu), dn, bb0);
            float v1 = fmaf(a1 + bf2f(sv.x >> 16),     dn, bb1);
            float v2 = fmaf(a2 + bf2f(sv.y & 0xFFFFu), dn, bb2);
            float v3 = fmaf(a3 + bf2f(sv.y >> 16),     dn, bb3);
            float v4 = fmaf(a4 + bf2f(sv.z & 0xFFFFu), dn, bb4);
            float v5 = fmaf(a5 + bf2f(sv.z >> 16),     dn, bb5);
            float v6 = fmaf(a6 + bf2f(sv.w & 0xFFFFu), dn, bb6);
            float v7 = fmaf(a7 + bf2f(sv.w >> 16),     dn, bb7);
            if (do_relu) {
                v0 = fmaxf(v0, 0.f); v1 = fmaxf(v1, 0.f); v2 = fmaxf(v2, 0.f); v3 = fmaxf(v3, 0.f);
                v4 = fmaxf(v4, 0.f); v5 = fmaxf(v5, 0.f); v6 = fmaxf(v6, 0.f); v7 = fmaxf(v7, 0.f);
            }
            u32x4 o;
            o.x = (unsigned int)f2bf(v0) | ((unsigned int)f2bf(v1) << 16);
            o.y = (unsigned int)f2bf(v2) | ((unsigned int)f2bf(v3) << 16);
            o.z = (unsigned int)f2bf(v4) | ((unsigned int)f2bf(v5) << 16);
            o.w = (unsigned int)f2bf(v6) | ((unsigned int)f2bf(v7) << 16);
            op[(size_t)node * 2 + half] = o;
        }
    }
}

// ---------------- fused mean-pool + linear head (1 graph/block, coalesced) ----
__global__ __launch_bounds__(256) void k_pool_final(const int* __restrict__ gptr,
                             const unsigned short* __restrict__ h,   // slice-major
                             const void* __restrict__ Wl, const void* __restrict__ bl,
                             void* __restrict__ out, const int* __restrict__ flags) {
    int F32 = flags[0];
    __shared__ float part[4];
    int g = blockIdx.x;
    int s = threadIdx.x >> 6;        // slice = wave
    int lane = threadIdx.x & 63;
    int nsub = lane >> 3, up = lane & 7;
    int s0 = gptr[g], e0 = gptr[g + 1];
    const unsigned int* xsl = (const unsigned int*)h + (size_t)s * N_NODES * 8;
    float a0 = 0.f, a1 = 0.f;
    for (int n = s0 + nsub; n < e0; n += 8) {
        unsigned int v = xsl[(size_t)n * 8 + up];
        a0 += bf2f(v & 0xFFFFu);
        a1 += bf2f(v >> 16);
    }
    a0 += __shfl_down(a0, 32, 64); a1 += __shfl_down(a1, 32, 64);
    a0 += __shfl_down(a0, 16, 64); a1 += __shfl_down(a1, 16, 64);
    a0 += __shfl_down(a0, 8, 64);  a1 += __shfl_down(a1, 8, 64);
    float v = 0.f;
    if (nsub == 0) {
        float cnt = fmaxf((float)(e0 - s0), 1.0f);
        int f = s * 16 + up * 2;
        v = (a0 / cnt) * loadf(Wl, f, F32) + (a1 / cnt) * loadf(Wl, f + 1, F32);
    }
    v += __shfl_down(v, 4, 64);
    v += __shfl_down(v, 2, 64);
    v += __shfl_down(v, 1, 64);
    if (lane == 0) part[s] = v;
    __syncthreads();
    if (threadIdx.x == 0) {
        float r = part[0] + part[1] + part[2] + part[3] + loadf(bl, 0, F32);
        if (F32) ((float*)out)[g] = r;
        else     ((__hip_bfloat16*)out)[g] = __float2bfloat16(r);
    }
}

extern "C" void kernel_launch(void* const* d_in, const int* in_sizes, int n_in,
                              void* d_out, int out_size, void* d_ws, size_t ws_size,
                              hipStream_t stream) {
    const void* x     = d_in[0];
    const void* ei    = d_in[1];
    const void* batch = d_in[2];
    const void* W1 = d_in[3];
    const void* b1 = d_in[4];
    const void* W2 = d_in[5];
    const void* b2 = d_in[6];
    const void* W3 = d_in[7];
    const void* b3 = d_in[8];
    const void* Wl = d_in[9];
    const void* bl = d_in[10];

    // workspace layout (~41 MB)
    float* dis   = (float*)d_ws;             // 100352
    int*   cnt   = (int*)(dis + 100352);     // 100352
    int*   rp    = cnt + 100352;             // 100352 (needs 100001)
    int*   csr   = rp + 100352;              // 1600000
    int*   gcnt  = csr + 1600000;            // 1024
    int*   gptr  = gcnt + 1024;              // 1056 (needs 1025)
    int*   partN = gptr + 1056;              // 512
    int*   bcnt  = partN + 512;              // 256
    int*   flags = bcnt + 256;               // 16
    unsigned int* packed = (unsigned int*)(flags + 16);    // NB*BCAP (7.8 MB)
    unsigned short* bufA = (unsigned short*)(packed + (size_t)NB * BCAP);  // bf16 slice-major (12.8 MB)
    unsigned short* bufB = bufA + (size_t)NSLICE * N_NODES * 16;           // bf16 slice-major (12.8 MB)

    const int TB = 256;
    dim3 blk(TB);
    int gN = (N_NODES + TB - 1) / TB;        // 391
    // gather grid: 782 group-pairs x 8 xcd-slots -> grp 0..1563 covers 100096 nodes
    int gGA = 782 * 8;

    // init: detect + zero small counters
    k_init<<<1, blk, 0, stream>>>((const unsigned int*)x, (const unsigned int*)ei,
                                  flags, gcnt, bcnt);
    // phase A partition (two-pass fat blocks with LDS staging, + batch counts)
    k_part<<<(N_EDGES + EPB - 1) / EPB, blk, 0, stream>>>(ei, batch, bcnt, gcnt, packed, flags);
    // hist: cnt + dis + scan partials
    k_hist<<<NBU, blk, 0, stream>>>(packed, bcnt, cnt, dis, partN);
    // middle scan: partN exclusive + rp[N] + graph scan -> gptr
    k_scan_mid<<<1, 512, 0, stream>>>(partN, gN, rp, N_NODES, gcnt, gptr);
    // p3: rp
    k_scan_p3<<<gN, blk, 0, stream>>>(cnt, partN, rp, N_NODES);
    // phase B: dense csr (sorted by dst)
    k_bucketcsr<<<NBU, 512, 0, stream>>>(packed, bcnt, rp, csr);

    // ---- layer 1 ----
    k_gemm<F_IN><<<1024, blk, 0, stream>>>(x, W1, dis, bufA, flags, -1, 0);
    k_gather_sm<<<gGA, blk, 0, stream>>>(rp, csr, dis, bufA, b1, bufB, 1, flags);
    // ---- layer 2 ----
    k_gemm<HID><<<1024, blk, 0, stream>>>(bufB, W2, dis, bufA, flags, 0, 1);
    k_gather_sm<<<gGA, blk, 0, stream>>>(rp, csr, dis, bufA, b2, bufB, 1, flags);
    // ---- layer 3 ----
    k_gemm<HID><<<1024, blk, 0, stream>>>(bufB, W3, dis, bufA, flags, 0, 1);
    k_gather_sm<<<gGA, blk, 0, stream>>>(rp, csr, dis, bufA, b3, bufB, 0, flags);

    // ---- pool + head ----
    k_pool_final<<<N_GRAPHS, blk, 0, stream>>>(gptr, bufB, Wl, bl, d_out, flags);
}

// Round 7
// 345.830 us; speedup vs baseline: 6.5228x; 1.0129x over previous
//
#include <hip/hip_runtime.h>
#include <hip/hip_bf16.h>

#define N_NODES 100000
#define N_EDGES 1600000
#define F_IN 128
#define HID 64
#define N_GRAPHS 1024

// fine dst-partition: bucket = dst>>9 (512 nodes/bucket)
#define SH 9
#define NBU 196        // buckets used: ceil(100000/512)
#define NB 200         // allocated
#define BCAP 9728      // mean 8192 + 17 sigma
#define EPB 8192       // edges per k_part block (196 blocks exactly)
#define NSLICE 2       // R6: 2 slices x 32 feats (64-B rows) -> one full cache
                       // line per edge-slice request; slice = 6.4 MB (~60% XCD L2)

typedef __attribute__((ext_vector_type(8))) short bf16x8;
typedef __attribute__((ext_vector_type(4))) float f32x4;
typedef __attribute__((ext_vector_type(4))) unsigned int u32x4;

// ---------------- bf16 bit helpers --------------------------------------------
__device__ __forceinline__ unsigned short f2bf(float f) {
    __hip_bfloat16 h = __float2bfloat16(f);   // RNE
    return *reinterpret_cast<unsigned short*>(&h);
}
__device__ __forceinline__ float bf2f(unsigned int u) {
    return __uint_as_float(u << 16);
}

// ---------------- dual-path load helpers (wire dtype resolved at runtime) -----
__device__ __forceinline__ float loadf(const void* p, size_t i, int f32) {
    if (f32) return ((const float*)p)[i];
    return __bfloat162float(((const __hip_bfloat16*)p)[i]);
}
__device__ __forceinline__ int loadi(const void* p, size_t i, int i64) {
    if (i64) return (int)((const long long*)p)[i];
    return ((const int*)p)[i];
}

// ---------------- init: wire detect + zero small counters ---------------------
__global__ void k_init(const unsigned int* __restrict__ xw_,
                       const unsigned int* __restrict__ ei_,
                       int* __restrict__ flags,
                       int* __restrict__ gcnt, int* __restrict__ bcnt) {
    __shared__ int cnt_f, cnt_i;
    int t = threadIdx.x;
    if (t == 0) { cnt_f = 0; cnt_i = 0; }
    __syncthreads();
    unsigned int w = xw_[t];
    unsigned int e = (w >> 7) & 0xFFu;
    if (e >= 100u && e <= 140u) atomicAdd(&cnt_f, 1);
    unsigned int iw = ei_[2 * t + 1];
    if (iw == 0u) atomicAdd(&cnt_i, 1);
    for (int i = t; i < N_GRAPHS; i += 256) gcnt[i] = 0;
    for (int i = t; i < NB; i += 256) bcnt[i] = 0;
    __syncthreads();
    if (t == 0) {
        flags[0] = (cnt_f < 180) ? 1 : 0;   // 1 => fp32 wire
        flags[1] = (cnt_i >= 128) ? 1 : 0;  // 1 => int64 wire
    }
}

// ---------------- phase A: partition by dst>>9, two-pass fat blocks -----------
// R4: pass 1 stages packed word + bucket id in LDS; pass 2 re-reads LDS instead
// of re-reading edge_index from global (-12.8 MB int64 traffic, -1.6M decodes).
__global__ __launch_bounds__(256) void k_part(const void* __restrict__ ei,
                                              const void* __restrict__ batch,
                                              int* __restrict__ bcnt,
                                              int* __restrict__ gcnt,
                                              unsigned int* __restrict__ packed,
                                              const int* __restrict__ flags) {
    int I64 = flags[1];
    __shared__ int hist[NB];
    __shared__ int base[NB];
    __shared__ int ghist[N_GRAPHS];        // 4 KB
    __shared__ unsigned int elds[EPB];     // 32 KB: packed words
    __shared__ unsigned char ebkt[EPB];    // 8 KB: bucket ids (0xFF = invalid)
    int t = threadIdx.x;
    if (t < NB) hist[t] = 0;
    for (int i = t; i < N_GRAPHS; i += 256) ghist[i] = 0;
    __syncthreads();
    // batch counting: block covers nodes [blk*512, blk*512+512)
    for (int it = 0; it < 2; ++it) {
        int n = blockIdx.x * 512 + it * 256 + t;
        if (n < N_NODES) atomicAdd(&ghist[loadi(batch, n, I64)], 1);
    }
    // edge pass 1: decode once, stage in LDS, bucket counts
    int e0 = blockIdx.x * EPB;
#pragma unroll 4
    for (int it = 0; it < EPB / 256; ++it) {
        int idx = it * 256 + t;
        int e = e0 + idx;
        unsigned int pv = 0u;
        unsigned char bk = 0xFFu;
        if (e < N_EDGES) {
            int sN = loadi(ei, e, I64);
            int d = loadi(ei, (size_t)N_EDGES + e, I64);
            bk = (unsigned char)(d >> SH);
            pv = ((unsigned int)sN << SH) | (unsigned int)(d & 511);
            atomicAdd(&hist[d >> SH], 1);
        }
        elds[idx] = pv;
        ebkt[idx] = bk;
    }
    __syncthreads();
    if (t < NB) {
        base[t] = hist[t] ? atomicAdd(&bcnt[t], hist[t]) : 0;
        hist[t] = 0;   // reuse as pass-2 rank counter
    }
    for (int i = t; i < N_GRAPHS; i += 256)
        if (ghist[i]) atomicAdd(&gcnt[i], ghist[i]);
    __syncthreads();
    // edge pass 2: rank + write from LDS
#pragma unroll 4
    for (int it = 0; it < EPB / 256; ++it) {
        int idx = it * 256 + t;
        unsigned char bk = ebkt[idx];
        if (bk != 0xFFu) {
            unsigned int pv = elds[idx];
            int r = atomicAdd(&hist[bk], 1);
            int pos = base[bk] + r;
            if (pos < BCAP)
                packed[(size_t)bk * BCAP + pos] = pv;
        }
    }
}

// ---------------- hist: in-degree + dis + scan partials (fused) ---------------
__global__ __launch_bounds__(256) void k_hist(const unsigned int* __restrict__ packed,
                                              const int* __restrict__ bcnt,
                                              int* __restrict__ cnt,
                                              float* __restrict__ dis,
                                              int* __restrict__ partN) {
    __shared__ int hist[512];
    int b = blockIdx.x;
    int t = threadIdx.x;
    int n = bcnt[b];
    if (n > BCAP) n = BCAP;
    for (int i = t; i < 512; i += 256) hist[i] = 0;
    __syncthreads();
    const unsigned int* pb = packed + (size_t)b * BCAP;
    for (int i = t; i < n; i += 256)
        atomicAdd(&hist[pb[i] & 511u], 1);
    __syncthreads();
    int nbase = b << SH;
    for (int i = t; i < 512; i += 256) {
        int node = nbase + i;
        if (node < N_NODES) {
            int c = hist[i];
            cnt[node] = c;
            dis[node] = rsqrtf((float)c + 1.0f);
        }
    }
    __syncthreads();
    for (int off = 128; off > 0; off >>= 1) {
        if (t < off) { hist[t] += hist[t + off]; hist[256 + t] += hist[256 + t + off]; }
        __syncthreads();
    }
    if (t == 0) {
        partN[2 * b] = hist[0];
        if (2 * b + 1 < 391) partN[2 * b + 1] = hist[256];
    }
}

// ---------------- middle scan: partN (391) + graph scan (1024), one block -----
__global__ void k_scan_mid(int* __restrict__ partial, int nb,
                           int* __restrict__ rp, int n,
                           const int* __restrict__ gcnt, int* __restrict__ gptr) {
    __shared__ int s[512];
    int t = threadIdx.x;
    int v = (t < nb) ? partial[t] : 0;
    s[t] = v;
    __syncthreads();
    for (int off = 1; off < 512; off <<= 1) {
        int x = (t >= off) ? s[t - off] : 0;
        __syncthreads();
        s[t] += x;
        __syncthreads();
    }
    if (t < nb) partial[t] = s[t] - v;   // exclusive
    if (t == 511) rp[n] = s[511];        // grand total
    __syncthreads();
    int a = gcnt[2 * t], bq = gcnt[2 * t + 1];
    int ps = a + bq;
    s[t] = ps;
    __syncthreads();
    for (int off = 1; off < 512; off <<= 1) {
        int x = (t >= off) ? s[t - off] : 0;
        __syncthreads();
        s[t] += x;
        __syncthreads();
    }
    int excl = s[t] - ps;
    gptr[2 * t] = excl;
    gptr[2 * t + 1] = excl + a;
    if (t == 511) gptr[1024] = s[511];
}

// ---------------- scan p3: per-256-chunk local scan + offset -> rp ------------
__global__ void k_scan_p3(const int* __restrict__ in, const int* __restrict__ partial,
                          int* __restrict__ out, int n) {
    __shared__ int s[256];
    int t = threadIdx.x;
    int i = blockIdx.x * 256 + t;
    int v = (i < n) ? in[i] : 0;
    s[t] = v;
    __syncthreads();
    for (int off = 1; off < 256; off <<= 1) {
        int x = (t >= off) ? s[t - off] : 0;
        __syncthreads();
        s[t] += x;
        __syncthreads();
    }
    if (i < n) out[i] = partial[blockIdx.x] + s[t] - v;
}

// ---------------- phase B: LDS counting-sort, dense csr writes ----------------
__global__ __launch_bounds__(512) void k_bucketcsr(const unsigned int* __restrict__ packed,
                                                   const int* __restrict__ bcnt,
                                                   const int* __restrict__ rp,
                                                   int* __restrict__ csr) {
    __shared__ int offs[512];
    __shared__ int elds[BCAP];    // 38 KB
    int b = blockIdx.x;
    int nbase = b << SH;
    int base = rp[nbase];
    int lim = nbase + 512; if (lim > N_NODES) lim = N_NODES;
    int nedge = rp[lim] - base;
    if (nedge > BCAP) nedge = BCAP;
    for (int i = threadIdx.x; i < 512; i += 512) {
        int node = nbase + i;
        offs[i] = (node < N_NODES) ? (rp[node] - base) : nedge;
    }
    __syncthreads();
    int n = bcnt[b]; if (n > BCAP) n = BCAP;
    const unsigned int* pb = packed + (size_t)b * BCAP;
    for (int i = threadIdx.x; i < n; i += 512) {
        unsigned int p = pb[i];
        int pos = atomicAdd(&offs[p & 511u], 1);
        if (pos < BCAP) elds[pos] = (int)(p >> SH);
    }
    __syncthreads();
    for (int i = threadIdx.x; i < nedge; i += 512)
        csr[base + i] = elds[i];
}

// ---------------- MFMA GEMM: in[N,K] @ W[K,64] -> out slice-major bf16 --------
// out layout: [2 slices][N_NODES][32 feats] bf16: slice s is a contiguous
// 6.4 MB block; 64-B rows = one cache line per edge-slice gather request.
template <int K>
__global__ __launch_bounds__(256) void k_gemm(const void* __restrict__ x,
                                              const void* __restrict__ W,
                                              const float* __restrict__ dis,
                                              unsigned short* __restrict__ out,  // bf16 bits
                                              const int* __restrict__ flags,
                                              int x_is_f32, int in_sm) {
    int Wf32 = flags[0];
    int xF32 = (x_is_f32 < 0) ? Wf32 : x_is_f32;
    __shared__ unsigned short Wt[64][K + 8];
    __shared__ unsigned short xs[32][K + 8];
    int t = threadIdx.x;
    int wave = t >> 6, lane = t & 63;
    int quad = lane >> 4, l16 = lane & 15;

    for (int id = t; id < 64 * K; id += 256) {
        int k = id >> 6, n = id & 63;
        Wt[n][k] = f2bf(loadf(W, id, Wf32));
    }
    __syncthreads();

    bf16x8 bfrag[K / 32];
#pragma unroll
    for (int c = 0; c < K / 32; ++c)
        bfrag[c] = *reinterpret_cast<bf16x8*>(&Wt[wave * 16 + l16][c * 32 + quad * 8]);

    const int ngroups = (N_NODES + 31) / 32;
    for (int g = blockIdx.x; g < ngroups; g += gridDim.x) {
        __syncthreads();
        int row0 = g * 32;
        if (in_sm) {
            // slice-major input (K==64, [2][N][32]): per slice, 32 rows x 64 B
            // = 128 contiguous u32x4; 128 threads cover one slice.
            for (int cid = t; cid < 4 * K; cid += 256) {
                int slice = cid >> 7, i = cid & 127;
                int rr = i >> 2, qq = i & 3;
                int r = row0 + rr;
                u32x4 val = {0u, 0u, 0u, 0u};
                if (r < N_NODES)
                    val = ((const u32x4*)x)[((size_t)slice * N_NODES + row0) * 4 + i];
                *reinterpret_cast<u32x4*>(&xs[rr][slice * 32 + qq * 8]) = val;
            }
        } else {
            for (int cid = t; cid < 4 * K; cid += 256) {
                int rr = cid / (K / 8), c8 = cid % (K / 8);
                int r = row0 + rr;
                u32x4 val = {0u, 0u, 0u, 0u};
                if (r < N_NODES) {
                    size_t base = (size_t)r * K + c8 * 8;
                    if (xF32) {
                        const u32x4* xp = (const u32x4*)x;
                        u32x4 q0 = xp[base / 4];
                        u32x4 q1 = xp[base / 4 + 1];
                        val.x = f2bf(__uint_as_float(q0.x)) | ((unsigned int)f2bf(__uint_as_float(q0.y)) << 16);
                        val.y = f2bf(__uint_as_float(q0.z)) | ((unsigned int)f2bf(__uint_as_float(q0.w)) << 16);
                        val.z = f2bf(__uint_as_float(q1.x)) | ((unsigned int)f2bf(__uint_as_float(q1.y)) << 16);
                        val.w = f2bf(__uint_as_float(q1.z)) | ((unsigned int)f2bf(__uint_as_float(q1.w)) << 16);
                    } else {
                        val = ((const u32x4*)x)[base / 8];
                    }
                }
                *reinterpret_cast<u32x4*>(&xs[rr][c8 * 8]) = val;
            }
        }
        __syncthreads();

        f32x4 acc0 = {0.f, 0.f, 0.f, 0.f};
        f32x4 acc1 = {0.f, 0.f, 0.f, 0.f};
#pragma unroll
        for (int c = 0; c < K / 32; ++c) {
            bf16x8 a0 = *reinterpret_cast<bf16x8*>(&xs[l16][c * 32 + quad * 8]);
            bf16x8 a1 = *reinterpret_cast<bf16x8*>(&xs[16 + l16][c * 32 + quad * 8]);
            acc0 = __builtin_amdgcn_mfma_f32_16x16x32_bf16(a0, bfrag[c], acc0, 0, 0, 0);
            acc1 = __builtin_amdgcn_mfma_f32_16x16x32_bf16(a1, bfrag[c], acc1, 0, 0, 0);
        }
        // col = wave*16 + l16 -> slice = col>>5, within-slice feat = col&31
        int col = wave * 16 + l16;
        unsigned short* ow = out + (size_t)(col >> 5) * (N_NODES * 32);
        int f = col & 31;
#pragma unroll
        for (int reg = 0; reg < 4; ++reg) {
            int r0 = row0 + quad * 4 + reg;
            if (r0 < N_NODES) ow[(size_t)r0 * 32 + f] = f2bf(acc0[reg] * dis[r0]);
            int r1 = row0 + 16 + quad * 4 + reg;
            if (r1 < N_NODES) ow[(size_t)r1 * 32 + f] = f2bf(acc1[reg] * dis[r1]);
        }
    }
}

// ---------------- CSR shuffle-reduce gather, 64-B rows, 4-lane clusters -------
// R6 post-mortem: duration tracks L1-miss request count, not VALU. NSLICE=2:
// lane = nodesub(4) x eslot(4) x quarter(4); a (node,eslot) 4-lane cluster
// reads one full 64-B row = ONE cache-line request (was two 32-B). Requests
// per edge per layer: 4 -> 2. Slice 6.4 MB (~60% XCD-L2 resident, rest L3;
// latency TLP-covered). XCD affinity: xcd = blk&7, slice = xcd>>2.
__global__ __launch_bounds__(256) void k_gather_sm(const int* __restrict__ rp,
                                                   const int* __restrict__ csr,
                                                   const float* __restrict__ dis,
                                                   const unsigned short* __restrict__ xws,
                                                   const void* __restrict__ bias,
                                                   unsigned short* __restrict__ out,
                                                   int do_relu,
                                                   const int* __restrict__ flags) {
    int F32 = flags[0];
    int blk = blockIdx.x;
    int xcd = blk & 7;
    int s = xcd >> 2;                              // slice 0..1
    int grp = ((blk >> 3) << 2) | (xcd & 3);       // 64-node group
    int wave = threadIdx.x >> 6, lane = threadIdx.x & 63;
    int nodesub = lane >> 4;                       // 0..3
    int eslot = (lane >> 2) & 3;                   // 0..3
    int q = lane & 3;                              // 0..3 (16-B quarter of 64-B row)
    const u32x4* xs4 = (const u32x4*)(xws + (size_t)s * N_NODES * 32);  // row = 4 u32x4
    u32x4* op = (u32x4*)out + (size_t)s * N_NODES * 4;
    // per-lane bias: 8 bf16 feats of this (slice, quarter)
    float bb0 = loadf(bias, s * 32 + q * 8 + 0, F32);
    float bb1 = loadf(bias, s * 32 + q * 8 + 1, F32);
    float bb2 = loadf(bias, s * 32 + q * 8 + 2, F32);
    float bb3 = loadf(bias, s * 32 + q * 8 + 3, F32);
    float bb4 = loadf(bias, s * 32 + q * 8 + 4, F32);
    float bb5 = loadf(bias, s * 32 + q * 8 + 5, F32);
    float bb6 = loadf(bias, s * 32 + q * 8 + 6, F32);
    float bb7 = loadf(bias, s * 32 + q * 8 + 7, F32);
    int wbase = grp * 64 + wave * 16;

    for (int ni = 0; ni < 4; ++ni) {
        int node = wbase + ni * 4 + nodesub;
        int valid = node < N_NODES;
        int start = valid ? rp[node] : 0;
        int end = valid ? rp[node + 1] : 0;
        float a0 = 0.f, a1 = 0.f, a2 = 0.f, a3 = 0.f;
        float a4 = 0.f, a5 = 0.f, a6 = 0.f, a7 = 0.f;
        int j = start + eslot;
        if (j < end) {
            int src = csr[j];
            for (;;) {
                int jn = j + 4;
                int sn = (jn < end) ? csr[jn] : 0;   // prefetch next index
                u32x4 v = xs4[(size_t)src * 4 + q];
                a0 += bf2f(v.x & 0xFFFFu); a1 += bf2f(v.x >> 16);
                a2 += bf2f(v.y & 0xFFFFu); a3 += bf2f(v.y >> 16);
                a4 += bf2f(v.z & 0xFFFFu); a5 += bf2f(v.z >> 16);
                a6 += bf2f(v.w & 0xFFFFu); a7 += bf2f(v.w >> 16);
                if (jn >= end) break;
                j = jn; src = sn;
            }
        }
        // reduce over eslot (lane bits 2-3: offsets 4, 8)
#pragma unroll
        for (int off = 4; off <= 8; off <<= 1) {
            a0 += __shfl_down(a0, off, 64); a1 += __shfl_down(a1, off, 64);
            a2 += __shfl_down(a2, off, 64); a3 += __shfl_down(a3, off, 64);
            a4 += __shfl_down(a4, off, 64); a5 += __shfl_down(a5, off, 64);
            a6 += __shfl_down(a6, off, 64); a7 += __shfl_down(a7, off, 64);
        }
        if (((lane & 12) == 0) && valid) {   // eslot == 0: 16 lanes (4 nodes x 4 quarters)
            u32x4 sv = xs4[(size_t)node * 4 + q];   // self row (cache-hot)
            float dn = dis[node];
            float v0 = fmaf(a0 + bf2f(sv.x & 0xFFFFu), dn, bb0);
            float v1 = fmaf(a1 + bf2f(sv.x >> 16),     dn, bb1);
            float v2 = fmaf(a2 + bf2f(sv.y & 0xFFFFu), dn, bb2);
            float v3 = fmaf(a3 + bf2f(sv.y >> 16),     dn, bb3);
            float v4 = fmaf(a4 + bf2f(sv.z & 0xFFFFu), dn, bb4);
            float v5 = fmaf(a5 + bf2f(sv.z >> 16),     dn, bb5);
            float v6 = fmaf(a6 + bf2f(sv.w & 0xFFFFu), dn, bb6);
            float v7 = fmaf(a7 + bf2f(sv.w >> 16),     dn, bb7);
            if (do_relu) {
                v0 = fmaxf(v0, 0.f); v1 = fmaxf(v1, 0.f); v2 = fmaxf(v2, 0.f); v3 = fmaxf(v3, 0.f);
                v4 = fmaxf(v4, 0.f); v5 = fmaxf(v5, 0.f); v6 = fmaxf(v6, 0.f); v7 = fmaxf(v7, 0.f);
            }
            u32x4 o;
            o.x = (unsigned int)f2bf(v0) | ((unsigned int)f2bf(v1) << 16);
            o.y = (unsigned int)f2bf(v2) | ((unsigned int)f2bf(v3) << 16);
            o.z = (unsigned int)f2bf(v4) | ((unsigned int)f2bf(v5) << 16);
            o.w = (unsigned int)f2bf(v6) | ((unsigned int)f2bf(v7) << 16);
            op[(size_t)node * 4 + q] = o;
        }
    }
}

// ---------------- fused mean-pool + linear head (1 graph/block) ---------------
// [2][N][32] layout: 4 waves = 2 slices x 2 node-parity groups; lane =
// nodesub(4) x u32feat(16): each wave-instr reads 4 nodes x 64 B contiguous.
__global__ __launch_bounds__(256) void k_pool_final(const int* __restrict__ gptr,
                             const unsigned short* __restrict__ h,   // slice-major
                             const void* __restrict__ Wl, const void* __restrict__ bl,
                             void* __restrict__ out, const int* __restrict__ flags) {
    int F32 = flags[0];
    __shared__ float part[4];
    int g = blockIdx.x;
    int w = threadIdx.x >> 6;
    int s = w >> 1;                  // slice 0..1
    int wo = w & 1;                  // node parity group
    int lane = threadIdx.x & 63;
    int nsub = lane >> 4, up = lane & 15;
    int s0 = gptr[g], e0 = gptr[g + 1];
    const unsigned int* xsl = (const unsigned int*)h + (size_t)s * N_NODES * 16;
    float a0 = 0.f, a1 = 0.f;
    for (int n = s0 + wo * 4 + nsub; n < e0; n += 8) {
        unsigned int v = xsl[(size_t)n * 16 + up];
        a0 += bf2f(v & 0xFFFFu);
        a1 += bf2f(v >> 16);
    }
    a0 += __shfl_down(a0, 32, 64); a1 += __shfl_down(a1, 32, 64);
    a0 += __shfl_down(a0, 16, 64); a1 += __shfl_down(a1, 16, 64);
    float v = 0.f;
    if (nsub == 0) {
        float cnt = fmaxf((float)(e0 - s0), 1.0f);
        int f = s * 32 + up * 2;
        v = (a0 / cnt) * loadf(Wl, f, F32) + (a1 / cnt) * loadf(Wl, f + 1, F32);
    }
    v += __shfl_down(v, 8, 64);
    v += __shfl_down(v, 4, 64);
    v += __shfl_down(v, 2, 64);
    v += __shfl_down(v, 1, 64);
    if (lane == 0) part[w] = v;
    __syncthreads();
    if (threadIdx.x == 0) {
        float r = part[0] + part[1] + part[2] + part[3] + loadf(bl, 0, F32);
        if (F32) ((float*)out)[g] = r;
        else     ((__hip_bfloat16*)out)[g] = __float2bfloat16(r);
    }
}

extern "C" void kernel_launch(void* const* d_in, const int* in_sizes, int n_in,
                              void* d_out, int out_size, void* d_ws, size_t ws_size,
                              hipStream_t stream) {
    const void* x     = d_in[0];
    const void* ei    = d_in[1];
    const void* batch = d_in[2];
    const void* W1 = d_in[3];
    const void* b1 = d_in[4];
    const void* W2 = d_in[5];
    const void* b2 = d_in[6];
    const void* W3 = d_in[7];
    const void* b3 = d_in[8];
    const void* Wl = d_in[9];
    const void* bl = d_in[10];

    // workspace layout (~41 MB)
    float* dis   = (float*)d_ws;             // 100352
    int*   cnt   = (int*)(dis + 100352);     // 100352
    int*   rp    = cnt + 100352;             // 100352 (needs 100001)
    int*   csr   = rp + 100352;              // 1600000
    int*   gcnt  = csr + 1600000;            // 1024
    int*   gptr  = gcnt + 1024;              // 1056 (needs 1025)
    int*   partN = gptr + 1056;              // 512
    int*   bcnt  = partN + 512;              // 256
    int*   flags = bcnt + 256;               // 16
    unsigned int* packed = (unsigned int*)(flags + 16);    // NB*BCAP (7.8 MB)
    unsigned short* bufA = (unsigned short*)(packed + (size_t)NB * BCAP);  // bf16 slice-major (12.8 MB)
    unsigned short* bufB = bufA + (size_t)NSLICE * N_NODES * 32;           // bf16 slice-major (12.8 MB)

    const int TB = 256;
    dim3 blk(TB);
    int gN = (N_NODES + TB - 1) / TB;        // 391
    // gather grid: 391 group-quads x 8 xcd-slots -> grp 0..1563 covers 100096 nodes
    int gGA = 391 * 8;

    // init: detect + zero small counters
    k_init<<<1, blk, 0, stream>>>((const unsigned int*)x, (const unsigned int*)ei,
                                  flags, gcnt, bcnt);
    // phase A partition (two-pass fat blocks with LDS staging, + batch counts)
    k_part<<<(N_EDGES + EPB - 1) / EPB, blk, 0, stream>>>(ei, batch, bcnt, gcnt, packed, flags);
    // hist: cnt + dis + scan partials
    k_hist<<<NBU, blk, 0, stream>>>(packed, bcnt, cnt, dis, partN);
    // middle scan: partN exclusive + rp[N] + graph scan -> gptr
    k_scan_mid<<<1, 512, 0, stream>>>(partN, gN, rp, N_NODES, gcnt, gptr);
    // p3: rp
    k_scan_p3<<<gN, blk, 0, stream>>>(cnt, partN, rp, N_NODES);
    // phase B: dense csr (sorted by dst)
    k_bucketcsr<<<NBU, 512, 0, stream>>>(packed, bcnt, rp, csr);

    // ---- layer 1 ----
    k_gemm<F_IN><<<1024, blk, 0, stream>>>(x, W1, dis, bufA, flags, -1, 0);
    k_gather_sm<<<gGA, blk, 0, stream>>>(rp, csr, dis, bufA, b1, bufB, 1, flags);
    // ---- layer 2 ----
    k_gemm<HID><<<1024, blk, 0, stream>>>(bufB, W2, dis, bufA, flags, 0, 1);
    k_gather_sm<<<gGA, blk, 0, stream>>>(rp, csr, dis, bufA, b2, bufB, 1, flags);
    // ---- layer 3 ----
    k_gemm<HID><<<1024, blk, 0, stream>>>(bufB, W3, dis, bufA, flags, 0, 1);
    k_gather_sm<<<gGA, blk, 0, stream>>>(rp, csr, dis, bufA, b3, bufB, 0, flags);

    // ---- pool + head ----
    k_pool_final<<<N_GRAPHS, blk, 0, stream>>>(gptr, bufB, Wl, bl, d_out, flags);
}